// Round 1
// baseline (5788.295 us; speedup 1.0000x reference)
//
#include <hip/hip_runtime.h>
#include <math.h>

#define B_   8
#define NH_  8
#define D_   96
#define C_   768
#define N_   1569          // 8*14*14 + 1
#define NKV_ 393           // 8*7*7 + 1
#define M_   (B_*N_)       // 12552
#define QKV1 ((size_t)B_*NH_*N_*D_)    // 9,639,936 floats per tensor
#define KP1  ((size_t)B_*NH_*NKV_*D_)  // 2,414,592 floats
#define SCALE_ 0.10206207261596575f    // 96^-0.5

// ---------------------------------------------------------------------------
// GEMM: out = A[M_ x 768] * W[768 x NC] + bias
// BM=128 BN=128 BK=16, 256 threads, 8x8 per thread.
// SCATTER=true: NC=2304, scatter into q/k/v [B][NH][N][D] contiguous tensors.
// SCATTER=false: direct row-major store [M_ x NC].
// ---------------------------------------------------------------------------
template<int NC, bool SCATTER>
__global__ __launch_bounds__(256)
void gemm_kernel(const float* __restrict__ A, const float* __restrict__ W,
                 const float* __restrict__ bias, float* __restrict__ out)
{
    __shared__ float As[16][132];   // stored transposed: As[k][m]
    __shared__ float Bs[16][132];

    const int tid = threadIdx.x;
    const int ty = tid >> 4, tx = tid & 15;
    const int m0 = blockIdx.y * 128;
    const int n0 = blockIdx.x * 128;

    float acc[8][8];
    #pragma unroll
    for (int i = 0; i < 8; ++i)
        #pragma unroll
        for (int j = 0; j < 8; ++j) acc[i][j] = 0.f;

    for (int k0 = 0; k0 < 768; k0 += 16) {
        // A tile: 128 rows x 16 cols, 512 float4, 2 per thread, store transposed
        #pragma unroll
        for (int t = 0; t < 2; ++t) {
            const int i = tid + t * 256;
            const int r = i >> 2;
            const int c4 = (i & 3) * 4;
            int m = m0 + r; if (m >= M_) m = M_ - 1;     // clamp, discarded later
            const float4 v = *(const float4*)&A[(size_t)m * 768 + k0 + c4];
            As[c4 + 0][r] = v.x; As[c4 + 1][r] = v.y;
            As[c4 + 2][r] = v.z; As[c4 + 3][r] = v.w;
        }
        // B tile: 16 rows x 128 cols, 512 float4, 2 per thread
        #pragma unroll
        for (int t = 0; t < 2; ++t) {
            const int i = tid + t * 256;
            const int r2 = i >> 5;
            const int cc = (i & 31) * 4;
            const float4 v = *(const float4*)&W[(size_t)(k0 + r2) * NC + n0 + cc];
            *(float4*)&Bs[r2][cc] = v;
        }
        __syncthreads();
        #pragma unroll
        for (int kk = 0; kk < 16; ++kk) {
            float a[8], b[8];
            *(float4*)&a[0] = *(const float4*)&As[kk][ty * 8];
            *(float4*)&a[4] = *(const float4*)&As[kk][ty * 8 + 4];
            *(float4*)&b[0] = *(const float4*)&Bs[kk][tx * 8];
            *(float4*)&b[4] = *(const float4*)&Bs[kk][tx * 8 + 4];
            #pragma unroll
            for (int i = 0; i < 8; ++i)
                #pragma unroll
                for (int j = 0; j < 8; ++j) acc[i][j] += a[i] * b[j];
        }
        __syncthreads();
    }

    if constexpr (SCATTER) {
        #pragma unroll
        for (int i = 0; i < 8; ++i) {
            const int m = m0 + ty * 8 + i;
            if (m < M_) {
                const int bb2 = m / N_;
                const int n = m - bb2 * N_;
                #pragma unroll
                for (int j = 0; j < 8; ++j) {
                    const int c = n0 + tx * 8 + j;
                    const float val = acc[i][j] + bias[c];
                    const int s   = c / C_;           // 0=q,1=k,2=v
                    const int rem = c - s * C_;
                    const int hh  = rem / D_;
                    const int dd  = rem - hh * D_;
                    out[(size_t)s * QKV1 +
                        ((size_t)(bb2 * NH_ + hh) * N_ + n) * D_ + dd] = val;
                }
            }
        }
    } else {
        #pragma unroll
        for (int i = 0; i < 8; ++i) {
            const int m = m0 + ty * 8 + i;
            if (m < M_) {
                #pragma unroll
                for (int j = 0; j < 8; ++j) {
                    const int c = n0 + tx * 8 + j;
                    out[(size_t)m * NC + c] = acc[i][j] + bias[c];
                }
            }
        }
    }
}

// ---------------------------------------------------------------------------
// Depthwise 3x3x3 conv pool (+cls passthrough) then LayerNorm over D=96.
// One wave per output token; lane handles channels d=lane and d=64+lane(<32).
// in: [B*NH][N_][96]  out: [B*NH][ntok][96]
// ---------------------------------------------------------------------------
__global__ __launch_bounds__(256)
void pool_ln_kernel(const float* __restrict__ in, const float* __restrict__ cw,
                    const float* __restrict__ g, const float* __restrict__ bta,
                    float* __restrict__ out, int sHW, int oH, int oW)
{
    __shared__ float wsm[96 * 27];
    const int tid = threadIdx.x;
    for (int i = tid; i < 96 * 27; i += 256) wsm[i] = cw[i];
    __syncthreads();

    const int ntok  = 1 + 8 * oH * oW;
    const int total = 64 * ntok;       // B*NH tokens
    const int w = tid >> 6, lane = tid & 63;
    const int tok = blockIdx.x * 4 + w;
    if (tok >= total) return;

    const int bh = tok / ntok;
    const int nt = tok - bh * ntok;
    const size_t inbase = (size_t)bh * N_ * 96;
    const bool hi = (lane < 32);

    float v0, v1 = 0.f;
    if (nt == 0) {
        v0 = in[inbase + lane];
        if (hi) v1 = in[inbase + 64 + lane];
    } else {
        const int s  = nt - 1;
        const int to = s / (oH * oW);
        int r = s - to * (oH * oW);
        const int ho = r / oW;
        const int wo = r - ho * oW;
        const int ti0 = to - 1, hi0 = ho * sHW - 1, wi0 = wo * sHW - 1;
        float acc0 = 0.f, acc1 = 0.f;
        for (int dt = 0; dt < 3; ++dt) {
            const int t = ti0 + dt; if (t < 0 || t >= 8) continue;
            for (int dh = 0; dh < 3; ++dh) {
                const int h = hi0 + dh; if (h < 0 || h >= 14) continue;
                for (int dw = 0; dw < 3; ++dw) {
                    const int ww = wi0 + dw; if (ww < 0 || ww >= 14) continue;
                    const size_t tin = inbase + (size_t)(1 + (t * 14 + h) * 14 + ww) * 96;
                    const int tap = dt * 9 + dh * 3 + dw;
                    acc0 += wsm[lane * 27 + tap] * in[tin + lane];
                    if (hi) acc1 += wsm[(64 + lane) * 27 + tap] * in[tin + 64 + lane];
                }
            }
        }
        v0 = acc0; v1 = acc1;
    }
    // LayerNorm over 96 channels spread over the wave
    float sum = v0 + (hi ? v1 : 0.f);
    #pragma unroll
    for (int off = 32; off; off >>= 1) sum += __shfl_xor(sum, off, 64);
    float sq = v0 * v0 + (hi ? v1 * v1 : 0.f);
    #pragma unroll
    for (int off = 32; off; off >>= 1) sq += __shfl_xor(sq, off, 64);
    const float mu   = sum * (1.f / 96.f);
    const float var  = sq * (1.f / 96.f) - mu * mu;
    const float rstd = rsqrtf(var + 1e-5f);

    float* o = &out[(size_t)tok * 96];
    o[lane] = (v0 - mu) * rstd * g[lane] + bta[lane];
    if (hi) o[64 + lane] = (v1 - mu) * rstd * g[64 + lane] + bta[64 + lane];
}

// ---------------------------------------------------------------------------
// Attention: per (b,h) slab.  Q:[1569,96] K,V:[393,96].
// Block = 4 waves, 64 q-rows per block (wave: 2 rows x 8 iters).
// Phase A: q row in (uniform) VGPRs, lane-over-j K dots, softmax via shuffles,
//          probabilities into per-wave LDS row.
// Phase C: lane-over-d PV with float4 LDS broadcast of p, coalesced V loads.
// Output written as [B][N][C] (head-major in C).
// ---------------------------------------------------------------------------
__global__ __launch_bounds__(256)
void attn_kernel(const float* __restrict__ Q, const float* __restrict__ K,
                 const float* __restrict__ V, float* __restrict__ Out)
{
    __shared__ float s_sh[8][400];
    const int tid = threadIdx.x;
    const int w = tid >> 6, lane = tid & 63;
    const int bh = blockIdx.y;
    const int b = bh >> 3, hh = bh & 7;
    const size_t qbase  = (size_t)bh * N_ * D_;
    const size_t kvbase = (size_t)bh * NKV_ * D_;
    const bool hi = (lane < 32);
    const int d0 = lane, d1 = 64 + lane;

    for (int it = 0; it < 8; ++it) {
        const int r0 = blockIdx.x * 64 + it * 8 + w * 2;
        float linv[2] = {0.f, 0.f};

        #pragma unroll
        for (int ri = 0; ri < 2; ++ri) {
            const int row = r0 + ri;
            if (row < N_) {
                float qr[96];
                #pragma unroll
                for (int d4 = 0; d4 < 24; ++d4) {
                    const float4 v = *(const float4*)&Q[qbase + (size_t)row * 96 + d4 * 4];
                    qr[d4 * 4 + 0] = v.x; qr[d4 * 4 + 1] = v.y;
                    qr[d4 * 4 + 2] = v.z; qr[d4 * 4 + 3] = v.w;
                }
                float sloc[7];
                float mx = -INFINITY;
                #pragma unroll
                for (int jj = 0; jj < 7; ++jj) {
                    const int j = jj * 64 + lane;
                    if (j < NKV_) {
                        const float* kp = &K[kvbase + (size_t)j * 96];
                        float dot = 0.f;
                        #pragma unroll
                        for (int d4 = 0; d4 < 24; ++d4) {
                            const float4 kv = *(const float4*)&kp[d4 * 4];
                            dot += qr[d4*4+0]*kv.x + qr[d4*4+1]*kv.y
                                 + qr[d4*4+2]*kv.z + qr[d4*4+3]*kv.w;
                        }
                        sloc[jj] = dot * SCALE_;
                        mx = fmaxf(mx, sloc[jj]);
                    }
                }
                #pragma unroll
                for (int off = 32; off; off >>= 1) mx = fmaxf(mx, __shfl_xor(mx, off, 64));
                float lsum = 0.f;
                #pragma unroll
                for (int jj = 0; jj < 7; ++jj) {
                    const int j = jj * 64 + lane;
                    if (j < NKV_) {
                        const float p = __expf(sloc[jj] - mx);
                        s_sh[w * 2 + ri][j] = p;
                        lsum += p;
                    }
                }
                #pragma unroll
                for (int off = 32; off; off >>= 1) lsum += __shfl_xor(lsum, off, 64);
                linv[ri] = 1.f / lsum;
            }
        }
        __syncthreads();

        // Phase C: PV for both rows simultaneously
        {
            float a00 = 0.f, a01 = 0.f, a10 = 0.f, a11 = 0.f;
            for (int j4 = 0; j4 < 98; ++j4) {       // j = 0..391
                const float4 p0v = *(const float4*)&s_sh[w * 2 + 0][j4 * 4];
                const float4 p1v = *(const float4*)&s_sh[w * 2 + 1][j4 * 4];
                float p0a[4] = {p0v.x, p0v.y, p0v.z, p0v.w};
                float p1a[4] = {p1v.x, p1v.y, p1v.z, p1v.w};
                #pragma unroll
                for (int u = 0; u < 4; ++u) {
                    const int j = j4 * 4 + u;
                    const float* vp = &V[kvbase + (size_t)j * 96];
                    const float v0 = vp[d0];
                    a00 += p0a[u] * v0; a10 += p1a[u] * v0;
                    if (hi) {
                        const float v1 = vp[d1];
                        a01 += p0a[u] * v1; a11 += p1a[u] * v1;
                    }
                }
            }
            {   // tail j = 392
                const float p0 = s_sh[w * 2 + 0][392];
                const float p1 = s_sh[w * 2 + 1][392];
                const float* vp = &V[kvbase + (size_t)392 * 96];
                const float v0 = vp[d0];
                a00 += p0 * v0; a10 += p1 * v0;
                if (hi) {
                    const float v1 = vp[d1];
                    a01 += p0 * v1; a11 += p1 * v1;
                }
            }
            if (r0 < N_) {
                float* o = &Out[((size_t)(b * N_ + r0)) * 768 + hh * 96];
                o[d0] = a00 * linv[0];
                if (hi) o[d1] = a01 * linv[0];
            }
            if (r0 + 1 < N_) {
                float* o = &Out[((size_t)(b * N_ + r0 + 1)) * 768 + hh * 96];
                o[d0] = a10 * linv[1];
                if (hi) o[d1] = a11 * linv[1];
            }
        }
        __syncthreads();
    }
}

// ---------------------------------------------------------------------------
extern "C" void kernel_launch(void* const* d_in, const int* in_sizes, int n_in,
                              void* d_out, int out_size, void* d_ws, size_t ws_size,
                              hipStream_t stream)
{
    const float* x     = (const float*)d_in[0];
    const float* Wqkv  = (const float*)d_in[1];
    const float* bqkv  = (const float*)d_in[2];
    const float* Wproj = (const float*)d_in[3];
    const float* bproj = (const float*)d_in[4];
    const float* cwq   = (const float*)d_in[5];
    const float* cwk   = (const float*)d_in[6];
    const float* cwv   = (const float*)d_in[7];
    const float* lnqg  = (const float*)d_in[8];
    const float* lnqb  = (const float*)d_in[9];
    const float* lnkg  = (const float*)d_in[10];
    const float* lnkb  = (const float*)d_in[11];
    const float* lnvg  = (const float*)d_in[12];
    const float* lnvb  = (const float*)d_in[13];

    float* ws = (float*)d_ws;
    float* q_raw = ws;                      // [B][NH][N][D]
    float* k_raw = ws + QKV1;
    float* v_raw = ws + 2 * QKV1;
    float* q_p   = ws + 3 * QKV1;           // [B][NH][N][D]
    float* k_p   = ws + 4 * QKV1;           // [B][NH][NKV][D]
    float* v_p   = ws + 4 * QKV1 + KP1;
    float* attn_out = q_raw;                // alias: q_raw dead after pooling
    float* out = (float*)d_out;

    // 1) qkv GEMM with scatter into q/k/v [B][NH][N][D]
    gemm_kernel<2304, true><<<dim3(18, 99), 256, 0, stream>>>(x, Wqkv, bqkv, q_raw);

    // 2) pool + LN
    pool_ln_kernel<<<(64 * N_) / 4, 256, 0, stream>>>(q_raw, cwq, lnqg, lnqb, q_p, 1, 14, 14);
    pool_ln_kernel<<<(64 * NKV_ + 3) / 4, 256, 0, stream>>>(k_raw, cwk, lnkg, lnkb, k_p, 2, 7, 7);
    pool_ln_kernel<<<(64 * NKV_ + 3) / 4, 256, 0, stream>>>(v_raw, cwv, lnvg, lnvb, v_p, 2, 7, 7);

    // 3) attention -> [B][N][C]
    attn_kernel<<<dim3(25, 64), 256, 0, stream>>>(q_p, k_p, v_p, attn_out);

    // 4) output projection
    gemm_kernel<768, false><<<dim3(6, 99), 256, 0, stream>>>(attn_out, Wproj, bproj, out);
}

// Round 2
// 1052.650 us; speedup vs baseline: 5.4988x; 5.4988x over previous
//
#include <hip/hip_runtime.h>
#include <hip/hip_bf16.h>
#include <math.h>

#define B_   8
#define NH_  8
#define D_   96
#define C_   768
#define N_   1569          // 8*14*14 + 1
#define NKV_ 393           // 8*7*7 + 1
#define M_   (B_*N_)       // 12552
#define QKV1 ((size_t)B_*NH_*N_*D_)    // 9,639,936 floats per tensor
#define QPAD 1600          // padded q rows per slab (25 tiles of 64)
#define KPAD 416           // padded kv rows per slab (13 tiles of 32)
#define SCALE_ 0.10206207261596575f    // 96^-0.5

using short8v = __attribute__((ext_vector_type(8))) short;
using f32x4   = __attribute__((ext_vector_type(4))) float;
typedef unsigned short u16;

// ---------------------------------------------------------------------------
// GEMM: out = A[M_ x 768] * W[768 x NC] + bias   (fp32 vector FMA, unchanged)
// ---------------------------------------------------------------------------
template<int NC, bool SCATTER>
__global__ __launch_bounds__(256)
void gemm_kernel(const float* __restrict__ A, const float* __restrict__ W,
                 const float* __restrict__ bias, float* __restrict__ out)
{
    __shared__ float As[16][132];   // stored transposed: As[k][m]
    __shared__ float Bs[16][132];

    const int tid = threadIdx.x;
    const int ty = tid >> 4, tx = tid & 15;
    const int m0 = blockIdx.y * 128;
    const int n0 = blockIdx.x * 128;

    float acc[8][8];
    #pragma unroll
    for (int i = 0; i < 8; ++i)
        #pragma unroll
        for (int j = 0; j < 8; ++j) acc[i][j] = 0.f;

    for (int k0 = 0; k0 < 768; k0 += 16) {
        #pragma unroll
        for (int t = 0; t < 2; ++t) {
            const int i = tid + t * 256;
            const int r = i >> 2;
            const int c4 = (i & 3) * 4;
            int m = m0 + r; if (m >= M_) m = M_ - 1;
            const float4 v = *(const float4*)&A[(size_t)m * 768 + k0 + c4];
            As[c4 + 0][r] = v.x; As[c4 + 1][r] = v.y;
            As[c4 + 2][r] = v.z; As[c4 + 3][r] = v.w;
        }
        #pragma unroll
        for (int t = 0; t < 2; ++t) {
            const int i = tid + t * 256;
            const int r2 = i >> 5;
            const int cc = (i & 31) * 4;
            const float4 v = *(const float4*)&W[(size_t)(k0 + r2) * NC + n0 + cc];
            *(float4*)&Bs[r2][cc] = v;
        }
        __syncthreads();
        #pragma unroll
        for (int kk = 0; kk < 16; ++kk) {
            float a[8], b[8];
            *(float4*)&a[0] = *(const float4*)&As[kk][ty * 8];
            *(float4*)&a[4] = *(const float4*)&As[kk][ty * 8 + 4];
            *(float4*)&b[0] = *(const float4*)&Bs[kk][tx * 8];
            *(float4*)&b[4] = *(const float4*)&Bs[kk][tx * 8 + 4];
            #pragma unroll
            for (int i = 0; i < 8; ++i)
                #pragma unroll
                for (int j = 0; j < 8; ++j) acc[i][j] += a[i] * b[j];
        }
        __syncthreads();
    }

    if constexpr (SCATTER) {
        #pragma unroll
        for (int i = 0; i < 8; ++i) {
            const int m = m0 + ty * 8 + i;
            if (m < M_) {
                const int bb2 = m / N_;
                const int n = m - bb2 * N_;
                #pragma unroll
                for (int j = 0; j < 8; ++j) {
                    const int c = n0 + tx * 8 + j;
                    const float val = acc[i][j] + bias[c];
                    const int s   = c / C_;           // 0=q,1=k,2=v
                    const int rem = c - s * C_;
                    const int hh  = rem / D_;
                    const int dd  = rem - hh * D_;
                    out[(size_t)s * QKV1 +
                        ((size_t)(bb2 * NH_ + hh) * N_ + n) * D_ + dd] = val;
                }
            }
        }
    } else {
        #pragma unroll
        for (int i = 0; i < 8; ++i) {
            const int m = m0 + ty * 8 + i;
            if (m < M_) {
                #pragma unroll
                for (int j = 0; j < 8; ++j) {
                    const int c = n0 + tx * 8 + j;
                    out[(size_t)m * NC + c] = acc[i][j] + bias[c];
                }
            }
        }
    }
}

// ---------------------------------------------------------------------------
// Depthwise 3x3x3 conv pool (+cls) then LayerNorm over D=96; bf16 output into
// a zero-padded [64][tokstride][96] tensor.
// ---------------------------------------------------------------------------
__global__ __launch_bounds__(256)
void pool_ln_kernel(const float* __restrict__ in, const float* __restrict__ cw,
                    const float* __restrict__ g, const float* __restrict__ bta,
                    __hip_bfloat16* __restrict__ out, int sHW, int oH, int oW,
                    int tokstride)
{
    __shared__ float wsm[96 * 27];
    const int tid = threadIdx.x;
    for (int i = tid; i < 96 * 27; i += 256) wsm[i] = cw[i];
    __syncthreads();

    const int ntok  = 1 + 8 * oH * oW;
    const int total = 64 * ntok;       // B*NH tokens
    const int w = tid >> 6, lane = tid & 63;
    const int tok = blockIdx.x * 4 + w;
    if (tok >= total) return;

    const int bh = tok / ntok;
    const int nt = tok - bh * ntok;
    const size_t inbase = (size_t)bh * N_ * 96;
    const bool hi = (lane < 32);

    float v0, v1 = 0.f;
    if (nt == 0) {
        v0 = in[inbase + lane];
        if (hi) v1 = in[inbase + 64 + lane];
    } else {
        const int s  = nt - 1;
        const int to = s / (oH * oW);
        int r = s - to * (oH * oW);
        const int ho = r / oW;
        const int wo = r - ho * oW;
        const int ti0 = to - 1, hi0 = ho * sHW - 1, wi0 = wo * sHW - 1;
        float acc0 = 0.f, acc1 = 0.f;
        for (int dt = 0; dt < 3; ++dt) {
            const int t = ti0 + dt; if (t < 0 || t >= 8) continue;
            for (int dh = 0; dh < 3; ++dh) {
                const int h = hi0 + dh; if (h < 0 || h >= 14) continue;
                for (int dw = 0; dw < 3; ++dw) {
                    const int ww = wi0 + dw; if (ww < 0 || ww >= 14) continue;
                    const size_t tin = inbase + (size_t)(1 + (t * 14 + h) * 14 + ww) * 96;
                    const int tap = dt * 9 + dh * 3 + dw;
                    acc0 += wsm[lane * 27 + tap] * in[tin + lane];
                    if (hi) acc1 += wsm[(64 + lane) * 27 + tap] * in[tin + 64 + lane];
                }
            }
        }
        v0 = acc0; v1 = acc1;
    }
    float sum = v0 + (hi ? v1 : 0.f);
    #pragma unroll
    for (int off = 32; off; off >>= 1) sum += __shfl_xor(sum, off, 64);
    float sq = v0 * v0 + (hi ? v1 * v1 : 0.f);
    #pragma unroll
    for (int off = 32; off; off >>= 1) sq += __shfl_xor(sq, off, 64);
    const float mu   = sum * (1.f / 96.f);
    const float var  = sq * (1.f / 96.f) - mu * mu;
    const float rstd = rsqrtf(var + 1e-5f);

    __hip_bfloat16* o = &out[((size_t)bh * tokstride + nt) * 96];
    o[lane] = __float2bfloat16((v0 - mu) * rstd * g[lane] + bta[lane]);
    if (hi) o[64 + lane] = __float2bfloat16((v1 - mu) * rstd * g[64 + lane] + bta[64 + lane]);
}

// ---------------------------------------------------------------------------
// MFMA attention. Grid (25 q-tiles, 64 slabs), 4 waves/block, 16 q-rows/wave.
// No max-tracking: |s| <= 96*SCALE = 9.8 (LN-normalized rows) so exp(s) is
// overflow-safe in f32. S via mfma(Q,K^T); P routed C-layout -> A-frag layout
// through per-wave LDS (written in A-frag-linear order); PV via mfma(P,V).
// ---------------------------------------------------------------------------
__global__ __launch_bounds__(256)
void attn_mfma_kernel(const u16* __restrict__ Q, const u16* __restrict__ K,
                      const u16* __restrict__ V, float* __restrict__ Out)
{
    __shared__ alignas(16) u16 plds[4][512];   // per-wave 16x32 bf16 P tile
    const int tid  = threadIdx.x;
    const int w    = tid >> 6, lane = tid & 63;
    const int c    = lane & 15, g = lane >> 4;
    const int bh   = blockIdx.y;
    const int b    = bh >> 3, hh = bh & 7;
    const int q0   = blockIdx.x * 64 + w * 16;
    const int qrow = q0 + c;

    const size_t qbase = (size_t)bh * QPAD * 96;
    const size_t kbase = (size_t)bh * KPAD * 96;

    // Q A-frags: lane holds Q[qrow][kf*32 + g*8 .. +7]
    short8v qa[3];
    #pragma unroll
    for (int kf = 0; kf < 3; ++kf)
        qa[kf] = *(const short8v*)&Q[qbase + (size_t)qrow * 96 + kf * 32 + g * 8];

    f32x4 oacc[6];
    #pragma unroll
    for (int t = 0; t < 6; ++t) oacc[t] = (f32x4){0.f, 0.f, 0.f, 0.f};
    float lsum[4] = {0.f, 0.f, 0.f, 0.f};

    for (int pr = 0; pr < 13; ++pr) {          // 13 pairs of 16-col halves
        #pragma unroll
        for (int h = 0; h < 2; ++h) {
            const int j0   = pr * 32 + h * 16;
            const int jcol = j0 + c;
            const u16* kp = &K[kbase + (size_t)jcol * 96 + g * 8];
            short8v kb0 = *(const short8v*)&kp[0];
            short8v kb1 = *(const short8v*)&kp[32];
            short8v kb2 = *(const short8v*)&kp[64];
            f32x4 sacc = (f32x4){0.f, 0.f, 0.f, 0.f};
            sacc = __builtin_amdgcn_mfma_f32_16x16x32_bf16(qa[0], kb0, sacc, 0, 0, 0);
            sacc = __builtin_amdgcn_mfma_f32_16x16x32_bf16(qa[1], kb1, sacc, 0, 0, 0);
            sacc = __builtin_amdgcn_mfma_f32_16x16x32_bf16(qa[2], kb2, sacc, 0, 0, 0);
            #pragma unroll
            for (int r = 0; r < 4; ++r) {
                float s = sacc[r] * SCALE_;
                if (jcol >= NKV_) s = -1e30f;
                const float p = __expf(s);
                lsum[r] += p;
                // route (q = g*4+r, j = h*16+c) into A-frag-linear slot
                const int q    = g * 4 + r;
                const int j    = h * 16 + c;
                const int dstL = q | ((j >> 3) << 4);
                const int e    = j & 7;
                __hip_bfloat16 pb = __float2bfloat16(p);
                plds[w][dstL * 8 + e] = *(u16*)&pb;
            }
        }
        asm volatile("s_waitcnt lgkmcnt(0)" ::: "memory");
        const short8v pa = *(const short8v*)&plds[w][lane * 8];

        #pragma unroll
        for (int t = 0; t < 6; ++t) {
            const int d0 = t * 16;
            short8v vb;
            #pragma unroll
            for (int e = 0; e < 8; ++e)
                vb[e] = (short)V[kbase + (size_t)(pr * 32 + g * 8 + e) * 96 + d0 + c];
            oacc[t] = __builtin_amdgcn_mfma_f32_16x16x32_bf16(pa, vb, oacc[t], 0, 0, 0);
        }
    }

    float linv[4];
    #pragma unroll
    for (int r = 0; r < 4; ++r) {
        float s = lsum[r];
        s += __shfl_xor(s, 1, 64);
        s += __shfl_xor(s, 2, 64);
        s += __shfl_xor(s, 4, 64);
        s += __shfl_xor(s, 8, 64);
        linv[r] = 1.f / s;
    }

    #pragma unroll
    for (int t = 0; t < 6; ++t)
        #pragma unroll
        for (int r = 0; r < 4; ++r) {
            const int row = q0 + g * 4 + r;
            if (row < N_)
                Out[((size_t)(b * N_ + row)) * 768 + hh * 96 + t * 16 + c] =
                    oacc[t][r] * linv[r];
        }
}

// ---------------------------------------------------------------------------
extern "C" void kernel_launch(void* const* d_in, const int* in_sizes, int n_in,
                              void* d_out, int out_size, void* d_ws, size_t ws_size,
                              hipStream_t stream)
{
    const float* x     = (const float*)d_in[0];
    const float* Wqkv  = (const float*)d_in[1];
    const float* bqkv  = (const float*)d_in[2];
    const float* Wproj = (const float*)d_in[3];
    const float* bproj = (const float*)d_in[4];
    const float* cwq   = (const float*)d_in[5];
    const float* cwk   = (const float*)d_in[6];
    const float* cwv   = (const float*)d_in[7];
    const float* lnqg  = (const float*)d_in[8];
    const float* lnqb  = (const float*)d_in[9];
    const float* lnkg  = (const float*)d_in[10];
    const float* lnkb  = (const float*)d_in[11];
    const float* lnvg  = (const float*)d_in[12];
    const float* lnvb  = (const float*)d_in[13];

    float* ws = (float*)d_ws;
    float* q_raw = ws;                      // [B][NH][N][D] fp32
    float* k_raw = ws + QKV1;
    float* v_raw = ws + 2 * QKV1;
    __hip_bfloat16* q16 = (__hip_bfloat16*)(ws + 3 * QKV1);   // [64][1600][96]
    __hip_bfloat16* k16 = q16 + (size_t)64 * QPAD * 96;       // [64][416][96]
    __hip_bfloat16* v16 = k16 + (size_t)64 * KPAD * 96;
    float* attn_out = q_raw;                // alias: q_raw dead after pooling
    float* out = (float*)d_out;

    // 1) qkv GEMM with scatter into q/k/v [B][NH][N][D]
    gemm_kernel<2304, true><<<dim3(18, 99), 256, 0, stream>>>(x, Wqkv, bqkv, q_raw);

    // 2) zero the padded bf16 buffers (covers pad rows), then pool + LN
    const size_t bf16_total = ((size_t)64 * QPAD * 96 + 2 * (size_t)64 * KPAD * 96) * 2;
    hipMemsetAsync(q16, 0, bf16_total, stream);
    pool_ln_kernel<<<(64 * N_) / 4, 256, 0, stream>>>(q_raw, cwq, lnqg, lnqb, q16, 1, 14, 14, QPAD);
    pool_ln_kernel<<<(64 * NKV_ + 3) / 4, 256, 0, stream>>>(k_raw, cwk, lnkg, lnkb, k16, 2, 7, 7, KPAD);
    pool_ln_kernel<<<(64 * NKV_ + 3) / 4, 256, 0, stream>>>(v_raw, cwv, lnvg, lnvb, v16, 2, 7, 7, KPAD);

    // 3) MFMA attention -> [B][N][C] fp32
    attn_mfma_kernel<<<dim3(25, 64), 256, 0, stream>>>((const u16*)q16, (const u16*)k16,
                                                       (const u16*)v16, attn_out);

    // 4) output projection
    gemm_kernel<768, false><<<dim3(6, 99), 256, 0, stream>>>(attn_out, Wproj, bproj, out);
}

// Round 3
// 491.107 us; speedup vs baseline: 11.7862x; 2.1434x over previous
//
#include <hip/hip_runtime.h>
#include <hip/hip_bf16.h>
#include <math.h>

#define B_   8
#define NH_  8
#define D_   96
#define C_   768
#define N_   1569          // 8*14*14 + 1
#define NKV_ 393           // 8*7*7 + 1
#define M_   (B_*N_)       // 12552
#define MPAD 12672         // 99 tiles of 128
#define QKV1 ((size_t)B_*NH_*N_*D_)    // 9,639,936 floats per tensor
#define QPAD 1600          // padded q rows per slab (25 tiles of 64)
#define KPAD 416           // padded kv rows per slab (13 tiles of 32)
#define SCALE_ 0.10206207261596575f    // 96^-0.5

using short8v = __attribute__((ext_vector_type(8))) short;
using f32x4   = __attribute__((ext_vector_type(4))) float;
typedef unsigned short u16;

#define GLOAD_LDS16(g, l) __builtin_amdgcn_global_load_lds( \
    (const __attribute__((address_space(1))) void*)(g),     \
    (__attribute__((address_space(3))) void*)(l), 16, 0, 0)

static __device__ __forceinline__ u16 f2bf(float f) {
    __hip_bfloat16 b = __float2bfloat16(f);
    return *(u16*)&b;
}

// ---------------------------------------------------------------------------
// fp32 -> bf16 flat convert (n4 float4 chunks)
// ---------------------------------------------------------------------------
__global__ __launch_bounds__(256)
void cvt_f32_to_bf16(const float* __restrict__ in, u16* __restrict__ out, int n4)
{
    const int i = blockIdx.x * 256 + threadIdx.x;
    if (i < n4) {
        const float4 v = ((const float4*)in)[i];
        ushort4 o;
        o.x = f2bf(v.x); o.y = f2bf(v.y); o.z = f2bf(v.z); o.w = f2bf(v.w);
        ((ushort4*)out)[i] = o;
    }
}

// ---------------------------------------------------------------------------
// W [768][ncols] fp32  ->  Wt [ncols][768] bf16   (32x32 LDS tiles)
// ---------------------------------------------------------------------------
__global__ __launch_bounds__(256)
void transpose_cvt(const float* __restrict__ W, u16* __restrict__ Wt, int ncols)
{
    __shared__ float tile[32][33];
    const int tx = threadIdx.x & 31, ty = threadIdx.x >> 5;   // 32 x 8
    const int n0 = blockIdx.x * 32, k0 = blockIdx.y * 32;
    #pragma unroll
    for (int i = 0; i < 4; ++i)
        tile[ty + i * 8][tx] = W[(size_t)(k0 + ty + i * 8) * ncols + n0 + tx];
    __syncthreads();
    #pragma unroll
    for (int i = 0; i < 4; ++i)
        Wt[(size_t)(n0 + ty + i * 8) * 768 + k0 + tx] = f2bf(tile[tx][ty + i * 8]);
}

// ---------------------------------------------------------------------------
// bf16 MFMA GEMM: out = A[M_ x 768](bf16) * Bt[NC x 768](bf16)^T + bias (f32)
// BM=BN=128, BK=64, 4 waves (2x2), each wave 64x64 via 4x4 frags of 16x16x32.
// Staging via global_load_lds width 16 (m97 structure).
// SCATTER: qkv scatter into fp32 q/k/v [B][NH][N][D]; else row-major fp32.
// ---------------------------------------------------------------------------
template<int NC, bool SCATTER>
__global__ __launch_bounds__(256)
void gemm_bf16_kernel(const u16* __restrict__ A, const u16* __restrict__ Bt,
                      const float* __restrict__ bias, float* __restrict__ out)
{
    __shared__ alignas(16) u16 As[128 * 64];
    __shared__ alignas(16) u16 Bs[128 * 64];

    const int tid  = threadIdx.x;
    const int w    = tid >> 6, lane = tid & 63;
    const int c    = lane & 15, g = lane >> 4;
    const int wm   = w >> 1, wn = w & 1;
    const int m0   = blockIdx.y * 128, n0 = blockIdx.x * 128;
    const int lrow = lane >> 3;          // 0..7
    const int lcol = lane & 7;           // 0..7 (x8 bf16 = 16B)

    f32x4 acc[4][4];
    #pragma unroll
    for (int i = 0; i < 4; ++i)
        #pragma unroll
        for (int j = 0; j < 4; ++j) acc[i][j] = (f32x4){0.f, 0.f, 0.f, 0.f};

    for (int k0 = 0; k0 < 768; k0 += 64) {
        #pragma unroll
        for (int t = 0; t < 4; ++t) {
            const int r = t * 32 + w * 8;           // wave-uniform row base
            int m = m0 + r + lrow; if (m >= M_) m = M_ - 1;
            GLOAD_LDS16(&A[(size_t)m * 768 + k0 + lcol * 8], &As[r * 64]);
            GLOAD_LDS16(&Bt[(size_t)(n0 + r + lrow) * 768 + k0 + lcol * 8], &Bs[r * 64]);
        }
        __syncthreads();
        #pragma unroll
        for (int kk = 0; kk < 2; ++kk) {
            short8v a[4], b[4];
            #pragma unroll
            for (int i = 0; i < 4; ++i) {
                a[i] = *(const short8v*)&As[(wm * 64 + i * 16 + c) * 64 + kk * 32 + g * 8];
                b[i] = *(const short8v*)&Bs[(wn * 64 + i * 16 + c) * 64 + kk * 32 + g * 8];
            }
            #pragma unroll
            for (int i = 0; i < 4; ++i)
                #pragma unroll
                for (int j = 0; j < 4; ++j)
                    acc[i][j] = __builtin_amdgcn_mfma_f32_16x16x32_bf16(a[i], b[j], acc[i][j], 0, 0, 0);
        }
        __syncthreads();
    }

    #pragma unroll
    for (int i = 0; i < 4; ++i) {
        const int mrow = m0 + wm * 64 + i * 16 + g * 4;
        #pragma unroll
        for (int j = 0; j < 4; ++j) {
            const int ncol = n0 + wn * 64 + j * 16 + c;
            const float bv = bias[ncol];
            if constexpr (SCATTER) {
                const int s   = ncol / C_;          // 0=q,1=k,2=v
                const int rem = ncol - s * C_;
                const int hh  = rem / D_;
                const int dd  = rem - hh * D_;
                #pragma unroll
                for (int r = 0; r < 4; ++r) {
                    const int m = mrow + r;
                    if (m < M_) {
                        const int bb2 = m / N_;
                        const int n = m - bb2 * N_;
                        out[(size_t)s * QKV1 +
                            ((size_t)(bb2 * NH_ + hh) * N_ + n) * D_ + dd] = acc[i][j][r] + bv;
                    }
                }
            } else {
                #pragma unroll
                for (int r = 0; r < 4; ++r) {
                    const int m = mrow + r;
                    if (m < M_) out[(size_t)m * NC + ncol] = acc[i][j][r] + bv;
                }
            }
        }
    }
}

// ---------------------------------------------------------------------------
// Depthwise 3x3x3 conv pool (+cls) then LayerNorm over D=96; bf16 output into
// a zero-padded [64][tokstride][96] tensor.
// ---------------------------------------------------------------------------
__global__ __launch_bounds__(256)
void pool_ln_kernel(const float* __restrict__ in, const float* __restrict__ cw,
                    const float* __restrict__ g, const float* __restrict__ bta,
                    __hip_bfloat16* __restrict__ out, int sHW, int oH, int oW,
                    int tokstride)
{
    __shared__ float wsm[96 * 27];
    const int tid = threadIdx.x;
    for (int i = tid; i < 96 * 27; i += 256) wsm[i] = cw[i];
    __syncthreads();

    const int ntok  = 1 + 8 * oH * oW;
    const int total = 64 * ntok;       // B*NH tokens
    const int w = tid >> 6, lane = tid & 63;
    const int tok = blockIdx.x * 4 + w;
    if (tok >= total) return;

    const int bh = tok / ntok;
    const int nt = tok - bh * ntok;
    const size_t inbase = (size_t)bh * N_ * 96;
    const bool hi = (lane < 32);

    float v0, v1 = 0.f;
    if (nt == 0) {
        v0 = in[inbase + lane];
        if (hi) v1 = in[inbase + 64 + lane];
    } else {
        const int s  = nt - 1;
        const int to = s / (oH * oW);
        int r = s - to * (oH * oW);
        const int ho = r / oW;
        const int wo = r - ho * oW;
        const int ti0 = to - 1, hi0 = ho * sHW - 1, wi0 = wo * sHW - 1;
        float acc0 = 0.f, acc1 = 0.f;
        for (int dt = 0; dt < 3; ++dt) {
            const int t = ti0 + dt; if (t < 0 || t >= 8) continue;
            for (int dh = 0; dh < 3; ++dh) {
                const int h = hi0 + dh; if (h < 0 || h >= 14) continue;
                for (int dw = 0; dw < 3; ++dw) {
                    const int ww = wi0 + dw; if (ww < 0 || ww >= 14) continue;
                    const size_t tin = inbase + (size_t)(1 + (t * 14 + h) * 14 + ww) * 96;
                    const int tap = dt * 9 + dh * 3 + dw;
                    acc0 += wsm[lane * 27 + tap] * in[tin + lane];
                    if (hi) acc1 += wsm[(64 + lane) * 27 + tap] * in[tin + 64 + lane];
                }
            }
        }
        v0 = acc0; v1 = acc1;
    }
    float sum = v0 + (hi ? v1 : 0.f);
    #pragma unroll
    for (int off = 32; off; off >>= 1) sum += __shfl_xor(sum, off, 64);
    float sq = v0 * v0 + (hi ? v1 * v1 : 0.f);
    #pragma unroll
    for (int off = 32; off; off >>= 1) sq += __shfl_xor(sq, off, 64);
    const float mu   = sum * (1.f / 96.f);
    const float var  = sq * (1.f / 96.f) - mu * mu;
    const float rstd = rsqrtf(var + 1e-5f);

    __hip_bfloat16* o = &out[((size_t)bh * tokstride + nt) * 96];
    o[lane] = __float2bfloat16((v0 - mu) * rstd * g[lane] + bta[lane]);
    if (hi) o[64 + lane] = __float2bfloat16((v1 - mu) * rstd * g[64 + lane] + bta[64 + lane]);
}

// ---------------------------------------------------------------------------
// MFMA attention -> bf16 output [M_][768] (row-major, head-major cols).
// ---------------------------------------------------------------------------
__global__ __launch_bounds__(256)
void attn_mfma_kernel(const u16* __restrict__ Q, const u16* __restrict__ K,
                      const u16* __restrict__ V, u16* __restrict__ Out)
{
    __shared__ alignas(16) u16 plds[4][512];   // per-wave 16x32 bf16 P tile
    const int tid  = threadIdx.x;
    const int w    = tid >> 6, lane = tid & 63;
    const int c    = lane & 15, g = lane >> 4;
    const int bh   = blockIdx.y;
    const int b    = bh >> 3, hh = bh & 7;
    const int q0   = blockIdx.x * 64 + w * 16;
    const int qrow = q0 + c;

    const size_t qbase = (size_t)bh * QPAD * 96;
    const size_t kbase = (size_t)bh * KPAD * 96;

    short8v qa[3];
    #pragma unroll
    for (int kf = 0; kf < 3; ++kf)
        qa[kf] = *(const short8v*)&Q[qbase + (size_t)qrow * 96 + kf * 32 + g * 8];

    f32x4 oacc[6];
    #pragma unroll
    for (int t = 0; t < 6; ++t) oacc[t] = (f32x4){0.f, 0.f, 0.f, 0.f};
    float lsum[4] = {0.f, 0.f, 0.f, 0.f};

    for (int pr = 0; pr < 13; ++pr) {
        #pragma unroll
        for (int h = 0; h < 2; ++h) {
            const int jcol = pr * 32 + h * 16 + c;
            const u16* kp = &K[kbase + (size_t)jcol * 96 + g * 8];
            short8v kb0 = *(const short8v*)&kp[0];
            short8v kb1 = *(const short8v*)&kp[32];
            short8v kb2 = *(const short8v*)&kp[64];
            f32x4 sacc = (f32x4){0.f, 0.f, 0.f, 0.f};
            sacc = __builtin_amdgcn_mfma_f32_16x16x32_bf16(qa[0], kb0, sacc, 0, 0, 0);
            sacc = __builtin_amdgcn_mfma_f32_16x16x32_bf16(qa[1], kb1, sacc, 0, 0, 0);
            sacc = __builtin_amdgcn_mfma_f32_16x16x32_bf16(qa[2], kb2, sacc, 0, 0, 0);
            #pragma unroll
            for (int r = 0; r < 4; ++r) {
                float s = sacc[r] * SCALE_;
                if (jcol >= NKV_) s = -1e30f;
                const float p = __expf(s);
                lsum[r] += p;
                const int q    = g * 4 + r;
                const int j    = h * 16 + c;
                const int dstL = q | ((j >> 3) << 4);
                plds[w][dstL * 8 + (j & 7)] = f2bf(p);
            }
        }
        asm volatile("s_waitcnt lgkmcnt(0)" ::: "memory");
        const short8v pa = *(const short8v*)&plds[w][lane * 8];

        #pragma unroll
        for (int t = 0; t < 6; ++t) {
            const int d0 = t * 16;
            short8v vb;
            #pragma unroll
            for (int e = 0; e < 8; ++e)
                vb[e] = (short)V[kbase + (size_t)(pr * 32 + g * 8 + e) * 96 + d0 + c];
            oacc[t] = __builtin_amdgcn_mfma_f32_16x16x32_bf16(pa, vb, oacc[t], 0, 0, 0);
        }
    }

    float linv[4];
    #pragma unroll
    for (int r = 0; r < 4; ++r) {
        float s = lsum[r];
        s += __shfl_xor(s, 1, 64);
        s += __shfl_xor(s, 2, 64);
        s += __shfl_xor(s, 4, 64);
        s += __shfl_xor(s, 8, 64);
        linv[r] = 1.f / s;
    }

    #pragma unroll
    for (int t = 0; t < 6; ++t)
        #pragma unroll
        for (int r = 0; r < 4; ++r) {
            const int row = q0 + g * 4 + r;
            if (row < N_)
                Out[((size_t)(b * N_ + row)) * 768 + hh * 96 + t * 16 + c] =
                    f2bf(oacc[t][r] * linv[r]);
        }
}

// ---------------------------------------------------------------------------
extern "C" void kernel_launch(void* const* d_in, const int* in_sizes, int n_in,
                              void* d_out, int out_size, void* d_ws, size_t ws_size,
                              hipStream_t stream)
{
    const float* x     = (const float*)d_in[0];
    const float* Wqkv  = (const float*)d_in[1];
    const float* bqkv  = (const float*)d_in[2];
    const float* Wproj = (const float*)d_in[3];
    const float* bproj = (const float*)d_in[4];
    const float* cwq   = (const float*)d_in[5];
    const float* cwk   = (const float*)d_in[6];
    const float* cwv   = (const float*)d_in[7];
    const float* lnqg  = (const float*)d_in[8];
    const float* lnqb  = (const float*)d_in[9];
    const float* lnkg  = (const float*)d_in[10];
    const float* lnkb  = (const float*)d_in[11];
    const float* lnvg  = (const float*)d_in[12];
    const float* lnvb  = (const float*)d_in[13];

    float* ws = (float*)d_ws;
    float* q_raw = ws;                      // [B][NH][N][D] fp32
    float* k_raw = ws + QKV1;
    float* v_raw = ws + 2 * QKV1;
    __hip_bfloat16* q16 = (__hip_bfloat16*)(ws + 3 * QKV1);   // [64][1600][96]
    __hip_bfloat16* k16 = q16 + (size_t)64 * QPAD * 96;       // [64][416][96]
    __hip_bfloat16* v16 = k16 + (size_t)64 * KPAD * 96;
    u16* x16    = (u16*)(v16 + (size_t)64 * KPAD * 96);       // [12552][768] bf16
    u16* Wqkvt  = x16 + (size_t)M_ * 768;                     // [2304][768] bf16
    u16* Wprojt = Wqkvt + (size_t)2304 * 768;                 // [768][768] bf16
    u16* attn16 = (u16*)q_raw;              // alias: q_raw dead after pooling
    float* out = (float*)d_out;

    // 0) converts / transposes
    cvt_f32_to_bf16<<<(M_ * 768 / 4 + 255) / 256, 256, 0, stream>>>(x, x16, M_ * 768 / 4);
    transpose_cvt<<<dim3(2304 / 32, 768 / 32), 256, 0, stream>>>(Wqkv, Wqkvt, 2304);
    transpose_cvt<<<dim3(768 / 32, 768 / 32), 256, 0, stream>>>(Wproj, Wprojt, 768);

    // 1) qkv GEMM (bf16 MFMA) with scatter into fp32 q/k/v [B][NH][N][D]
    gemm_bf16_kernel<2304, true><<<dim3(18, 99), 256, 0, stream>>>(x16, Wqkvt, bqkv, q_raw);

    // 2) zero the padded bf16 buffers (covers pad rows), then pool + LN
    const size_t bf16_total = ((size_t)64 * QPAD * 96 + 2 * (size_t)64 * KPAD * 96) * 2;
    hipMemsetAsync(q16, 0, bf16_total, stream);
    pool_ln_kernel<<<(64 * N_) / 4, 256, 0, stream>>>(q_raw, cwq, lnqg, lnqb, q16, 1, 14, 14, QPAD);
    pool_ln_kernel<<<(64 * NKV_ + 3) / 4, 256, 0, stream>>>(k_raw, cwk, lnkg, lnkb, k16, 2, 7, 7, KPAD);
    pool_ln_kernel<<<(64 * NKV_ + 3) / 4, 256, 0, stream>>>(v_raw, cwv, lnvg, lnvb, v16, 2, 7, 7, KPAD);

    // 3) MFMA attention -> bf16 [M_][768]
    attn_mfma_kernel<<<dim3(25, 64), 256, 0, stream>>>((const u16*)q16, (const u16*)k16,
                                                       (const u16*)v16, attn16);

    // 4) output projection (bf16 MFMA) -> fp32 d_out
    gemm_bf16_kernel<768, false><<<dim3(6, 99), 256, 0, stream>>>(attn16, Wprojt, bproj, out);
}

// Round 4
// 359.714 us; speedup vs baseline: 16.0914x; 1.3653x over previous
//
#include <hip/hip_runtime.h>
#include <hip/hip_bf16.h>
#include <math.h>

#define B_   8
#define NH_  8
#define D_   96
#define C_   768
#define N_   1569          // 8*14*14 + 1
#define NKV_ 393           // 8*7*7 + 1
#define M_   (B_*N_)       // 12552
#define QKV1 ((size_t)B_*NH_*N_*D_)    // 9,639,936 elems per tensor
#define QPAD 1600          // padded q rows per slab (25 tiles of 64)
#define KPAD 416           // padded kv rows per slab (13 tiles of 32)
#define SCALE_ 0.10206207261596575f    // 96^-0.5

using short8v = __attribute__((ext_vector_type(8))) short;
using f32x4   = __attribute__((ext_vector_type(4))) float;
typedef unsigned short u16;

#define GLOAD_LDS16(g, l) __builtin_amdgcn_global_load_lds( \
    (const __attribute__((address_space(1))) void*)(g),     \
    (__attribute__((address_space(3))) void*)(l), 16, 0, 0)

static __device__ __forceinline__ u16 f2bf(float f) {
    __hip_bfloat16 b = __float2bfloat16(f);
    return *(u16*)&b;
}
static __device__ __forceinline__ float bf2f(u16 v) {
    return __bfloat162float(*(const __hip_bfloat16*)&v);
}

// ---------------------------------------------------------------------------
// fp32 -> bf16 flat convert (n4 float4 chunks)
// ---------------------------------------------------------------------------
__global__ __launch_bounds__(256)
void cvt_f32_to_bf16(const float* __restrict__ in, u16* __restrict__ out, int n4)
{
    const int i = blockIdx.x * 256 + threadIdx.x;
    if (i < n4) {
        const float4 v = ((const float4*)in)[i];
        ushort4 o;
        o.x = f2bf(v.x); o.y = f2bf(v.y); o.z = f2bf(v.z); o.w = f2bf(v.w);
        ((ushort4*)out)[i] = o;
    }
}

// ---------------------------------------------------------------------------
// W [768][ncols] fp32  ->  Wt [ncols][768] bf16   (32x32 LDS tiles)
// ---------------------------------------------------------------------------
__global__ __launch_bounds__(256)
void transpose_cvt(const float* __restrict__ W, u16* __restrict__ Wt, int ncols)
{
    __shared__ float tile[32][33];
    const int tx = threadIdx.x & 31, ty = threadIdx.x >> 5;   // 32 x 8
    const int n0 = blockIdx.x * 32, k0 = blockIdx.y * 32;
    #pragma unroll
    for (int i = 0; i < 4; ++i)
        tile[ty + i * 8][tx] = W[(size_t)(k0 + ty + i * 8) * ncols + n0 + tx];
    __syncthreads();
    #pragma unroll
    for (int i = 0; i < 4; ++i)
        Wt[(size_t)(n0 + ty + i * 8) * 768 + k0 + tx] = f2bf(tile[tx][ty + i * 8]);
}

// ---------------------------------------------------------------------------
// bf16 MFMA GEMM: out = A[M_ x 768](bf16) * Bt[NC x 768](bf16)^T + bias (f32)
// SCATTER: bf16 scatter into q/k/v [B][NH][N][D]; else row-major fp32.
// ---------------------------------------------------------------------------
template<int NC, bool SCATTER>
__global__ __launch_bounds__(256)
void gemm_bf16_kernel(const u16* __restrict__ A, const u16* __restrict__ Bt,
                      const float* __restrict__ bias, void* __restrict__ outp)
{
    __shared__ alignas(16) u16 As[128 * 64];
    __shared__ alignas(16) u16 Bs[128 * 64];

    const int tid  = threadIdx.x;
    const int w    = tid >> 6, lane = tid & 63;
    const int c    = lane & 15, g = lane >> 4;
    const int wm   = w >> 1, wn = w & 1;
    const int m0   = blockIdx.y * 128, n0 = blockIdx.x * 128;
    const int lrow = lane >> 3;
    const int lcol = lane & 7;

    f32x4 acc[4][4];
    #pragma unroll
    for (int i = 0; i < 4; ++i)
        #pragma unroll
        for (int j = 0; j < 4; ++j) acc[i][j] = (f32x4){0.f, 0.f, 0.f, 0.f};

    for (int k0 = 0; k0 < 768; k0 += 64) {
        #pragma unroll
        for (int t = 0; t < 4; ++t) {
            const int r = t * 32 + w * 8;
            int m = m0 + r + lrow; if (m >= M_) m = M_ - 1;
            GLOAD_LDS16(&A[(size_t)m * 768 + k0 + lcol * 8], &As[r * 64]);
            GLOAD_LDS16(&Bt[(size_t)(n0 + r + lrow) * 768 + k0 + lcol * 8], &Bs[r * 64]);
        }
        __syncthreads();
        #pragma unroll
        for (int kk = 0; kk < 2; ++kk) {
            short8v a[4], b[4];
            #pragma unroll
            for (int i = 0; i < 4; ++i) {
                a[i] = *(const short8v*)&As[(wm * 64 + i * 16 + c) * 64 + kk * 32 + g * 8];
                b[i] = *(const short8v*)&Bs[(wn * 64 + i * 16 + c) * 64 + kk * 32 + g * 8];
            }
            #pragma unroll
            for (int i = 0; i < 4; ++i)
                #pragma unroll
                for (int j = 0; j < 4; ++j)
                    acc[i][j] = __builtin_amdgcn_mfma_f32_16x16x32_bf16(a[i], b[j], acc[i][j], 0, 0, 0);
        }
        __syncthreads();
    }

    #pragma unroll
    for (int i = 0; i < 4; ++i) {
        const int mrow = m0 + wm * 64 + i * 16 + g * 4;
        #pragma unroll
        for (int j = 0; j < 4; ++j) {
            const int ncol = n0 + wn * 64 + j * 16 + c;
            const float bv = bias[ncol];
            if constexpr (SCATTER) {
                u16* out = (u16*)outp;
                const int s   = ncol / C_;          // 0=q,1=k,2=v
                const int rem = ncol - s * C_;
                const int hh  = rem / D_;
                const int dd  = rem - hh * D_;
                #pragma unroll
                for (int r = 0; r < 4; ++r) {
                    const int m = mrow + r;
                    if (m < M_) {
                        const int bb2 = m / N_;
                        const int n = m - bb2 * N_;
                        out[(size_t)s * QKV1 +
                            ((size_t)(bb2 * NH_ + hh) * N_ + n) * D_ + dd] = f2bf(acc[i][j][r] + bv);
                    }
                }
            } else {
                float* out = (float*)outp;
                #pragma unroll
                for (int r = 0; r < 4; ++r) {
                    const int m = mrow + r;
                    if (m < M_) out[(size_t)m * NC + ncol] = acc[i][j][r] + bv;
                }
            }
        }
    }
}

// ---------------------------------------------------------------------------
// Row-per-wave depthwise 3x3x3 pool + LayerNorm (bf16 in, bf16 out, f32 math).
// Wave handles one output row (OW tokens) of one (to,ho); row NROWS = cls.
// Per (dt,dh) tap-plane, 14 input w-positions staged once in registers and
// reused by all OW outputs. oscale folds attention's 1/sqrt(D) into q.
// ---------------------------------------------------------------------------
template<int STRIDE, int OH, int OW>
__global__ __launch_bounds__(256)
void pool_ln_row_kernel(const u16* __restrict__ in, const float* __restrict__ cw,
                        const float* __restrict__ g, const float* __restrict__ bta,
                        u16* __restrict__ out, int tokstride, float oscale)
{
    __shared__ float wsm[96 * 27];
    const int tid = threadIdx.x;
    for (int i = tid; i < 96 * 27; i += 256) wsm[i] = cw[i];
    __syncthreads();

    const int w = tid >> 6, lane = tid & 63;
    const int bh = blockIdx.y;
    const int R = blockIdx.x * 4 + w;
    const int NROWS = 8 * OH;
    if (R > NROWS) return;

    const bool hi = lane < 32;
    const size_t inbase = (size_t)bh * N_ * 96;
    const int ch0 = lane, ch1 = 64 + (lane & 31);
    const float g0 = g[ch0], b0 = bta[ch0];
    const float g1 = g[ch1], b1 = bta[ch1];

    if (R == NROWS) {   // cls token: LN only
        float v0 = bf2f(in[inbase + ch0]);
        float v1 = bf2f(in[inbase + ch1]);
        float s = v0 + (hi ? v1 : 0.f);
        #pragma unroll
        for (int off = 32; off; off >>= 1) s += __shfl_xor(s, off, 64);
        float sq = v0 * v0 + (hi ? v1 * v1 : 0.f);
        #pragma unroll
        for (int off = 32; off; off >>= 1) sq += __shfl_xor(sq, off, 64);
        const float mu = s * (1.f / 96.f);
        const float rstd = rsqrtf(sq * (1.f / 96.f) - mu * mu + 1e-5f);
        u16* o = &out[(size_t)bh * tokstride * 96];
        o[ch0] = f2bf(((v0 - mu) * rstd * g0 + b0) * oscale);
        if (hi) o[ch1] = f2bf(((v1 - mu) * rstd * g1 + b1) * oscale);
        return;
    }

    const int to = R / OH, ho = R % OH;
    float a0[OW], a1[OW];
    #pragma unroll
    for (int wo = 0; wo < OW; ++wo) { a0[wo] = 0.f; a1[wo] = 0.f; }

    for (int dt = 0; dt < 3; ++dt) {
        const int t = to - 1 + dt;
        if (t < 0 || t >= 8) continue;
        for (int dh = 0; dh < 3; ++dh) {
            const int h = ho * STRIDE - 1 + dh;
            if (h < 0 || h >= 14) continue;
            // stage all 14 input w-positions for this (t,h)
            float x0[14], x1[14];
            #pragma unroll
            for (int iw = 0; iw < 14; ++iw) {
                const size_t tin = inbase + (size_t)(1 + (t * 14 + h) * 14 + iw) * 96;
                x0[iw] = bf2f(in[tin + ch0]);
                x1[iw] = bf2f(in[tin + ch1]);
            }
            const int tapb = dt * 9 + dh * 3;
            float wt0[3], wt1[3];
            #pragma unroll
            for (int dw = 0; dw < 3; ++dw) {
                wt0[dw] = wsm[ch0 * 27 + tapb + dw];
                wt1[dw] = wsm[ch1 * 27 + tapb + dw];
            }
            #pragma unroll
            for (int wo = 0; wo < OW; ++wo)
                #pragma unroll
                for (int dw = 0; dw < 3; ++dw) {
                    const int iw = wo * STRIDE - 1 + dw;
                    if (iw < 0 || iw >= 14) continue;   // compile-time
                    a0[wo] += wt0[dw] * x0[iw];
                    a1[wo] += wt1[dw] * x1[iw];
                }
        }
    }

    #pragma unroll
    for (int wo = 0; wo < OW; ++wo) {
        float s = a0[wo] + (hi ? a1[wo] : 0.f);
        #pragma unroll
        for (int off = 32; off; off >>= 1) s += __shfl_xor(s, off, 64);
        float sq = a0[wo] * a0[wo] + (hi ? a1[wo] * a1[wo] : 0.f);
        #pragma unroll
        for (int off = 32; off; off >>= 1) sq += __shfl_xor(sq, off, 64);
        const float mu = s * (1.f / 96.f);
        const float rstd = rsqrtf(sq * (1.f / 96.f) - mu * mu + 1e-5f);
        const int tok = 1 + (to * OH + ho) * OW + wo;
        u16* o = &out[((size_t)bh * tokstride + tok) * 96];
        o[ch0] = f2bf(((a0[wo] - mu) * rstd * g0 + b0) * oscale);
        if (hi) o[ch1] = f2bf(((a1[wo] - mu) * rstd * g1 + b1) * oscale);
    }
}

// ---------------------------------------------------------------------------
// MFMA attention -> bf16 output [M_][768] (Q pre-scaled by 1/sqrt(D)).
// ---------------------------------------------------------------------------
__global__ __launch_bounds__(256)
void attn_mfma_kernel(const u16* __restrict__ Q, const u16* __restrict__ K,
                      const u16* __restrict__ V, u16* __restrict__ Out)
{
    __shared__ alignas(16) u16 plds[4][512];   // per-wave 16x32 bf16 P tile
    const int tid  = threadIdx.x;
    const int w    = tid >> 6, lane = tid & 63;
    const int c    = lane & 15, g = lane >> 4;
    const int bh   = blockIdx.y;
    const int b    = bh >> 3, hh = bh & 7;
    const int q0   = blockIdx.x * 64 + w * 16;
    const int qrow = q0 + c;

    const size_t qbase = (size_t)bh * QPAD * 96;
    const size_t kbase = (size_t)bh * KPAD * 96;

    short8v qa[3];
    #pragma unroll
    for (int kf = 0; kf < 3; ++kf)
        qa[kf] = *(const short8v*)&Q[qbase + (size_t)qrow * 96 + kf * 32 + g * 8];

    f32x4 oacc[6];
    #pragma unroll
    for (int t = 0; t < 6; ++t) oacc[t] = (f32x4){0.f, 0.f, 0.f, 0.f};
    float lsum[4] = {0.f, 0.f, 0.f, 0.f};

    for (int pr = 0; pr < 13; ++pr) {
        #pragma unroll
        for (int h = 0; h < 2; ++h) {
            const int jcol = pr * 32 + h * 16 + c;
            const u16* kp = &K[kbase + (size_t)jcol * 96 + g * 8];
            short8v kb0 = *(const short8v*)&kp[0];
            short8v kb1 = *(const short8v*)&kp[32];
            short8v kb2 = *(const short8v*)&kp[64];
            f32x4 sacc = (f32x4){0.f, 0.f, 0.f, 0.f};
            sacc = __builtin_amdgcn_mfma_f32_16x16x32_bf16(qa[0], kb0, sacc, 0, 0, 0);
            sacc = __builtin_amdgcn_mfma_f32_16x16x32_bf16(qa[1], kb1, sacc, 0, 0, 0);
            sacc = __builtin_amdgcn_mfma_f32_16x16x32_bf16(qa[2], kb2, sacc, 0, 0, 0);
            #pragma unroll
            for (int r = 0; r < 4; ++r) {
                float s = sacc[r];
                if (jcol >= NKV_) s = -1e30f;
                const float p = __expf(s);
                lsum[r] += p;
                const int q    = g * 4 + r;
                const int j    = h * 16 + c;
                const int dstL = q | ((j >> 3) << 4);
                plds[w][dstL * 8 + (j & 7)] = f2bf(p);
            }
        }
        asm volatile("s_waitcnt lgkmcnt(0)" ::: "memory");
        const short8v pa = *(const short8v*)&plds[w][lane * 8];

        #pragma unroll
        for (int t = 0; t < 6; ++t) {
            const int d0 = t * 16;
            short8v vb;
            #pragma unroll
            for (int e = 0; e < 8; ++e)
                vb[e] = (short)V[kbase + (size_t)(pr * 32 + g * 8 + e) * 96 + d0 + c];
            oacc[t] = __builtin_amdgcn_mfma_f32_16x16x32_bf16(pa, vb, oacc[t], 0, 0, 0);
        }
    }

    float linv[4];
    #pragma unroll
    for (int r = 0; r < 4; ++r) {
        float s = lsum[r];
        s += __shfl_xor(s, 1, 64);
        s += __shfl_xor(s, 2, 64);
        s += __shfl_xor(s, 4, 64);
        s += __shfl_xor(s, 8, 64);
        linv[r] = 1.f / s;
    }

    #pragma unroll
    for (int t = 0; t < 6; ++t)
        #pragma unroll
        for (int r = 0; r < 4; ++r) {
            const int row = q0 + g * 4 + r;
            if (row < N_)
                Out[((size_t)(b * N_ + row)) * 768 + hh * 96 + t * 16 + c] =
                    f2bf(oacc[t][r] * linv[r]);
        }
}

// ---------------------------------------------------------------------------
extern "C" void kernel_launch(void* const* d_in, const int* in_sizes, int n_in,
                              void* d_out, int out_size, void* d_ws, size_t ws_size,
                              hipStream_t stream)
{
    const float* x     = (const float*)d_in[0];
    const float* Wqkv  = (const float*)d_in[1];
    const float* bqkv  = (const float*)d_in[2];
    const float* Wproj = (const float*)d_in[3];
    const float* bproj = (const float*)d_in[4];
    const float* cwq   = (const float*)d_in[5];
    const float* cwk   = (const float*)d_in[6];
    const float* cwv   = (const float*)d_in[7];
    const float* lnqg  = (const float*)d_in[8];
    const float* lnqb  = (const float*)d_in[9];
    const float* lnkg  = (const float*)d_in[10];
    const float* lnkb  = (const float*)d_in[11];
    const float* lnvg  = (const float*)d_in[12];
    const float* lnvb  = (const float*)d_in[13];

    u16* ws = (u16*)d_ws;
    u16* qkv_raw = ws;                       // 3 x [B][NH][N][D] bf16
    u16* q16 = qkv_raw + 3 * QKV1;           // [64][QPAD][96] bf16
    u16* k16 = q16 + (size_t)64 * QPAD * 96; // [64][KPAD][96]
    u16* v16 = k16 + (size_t)64 * KPAD * 96;
    u16* x16    = v16 + (size_t)64 * KPAD * 96;   // [12552][768] bf16
    u16* Wqkvt  = x16 + (size_t)M_ * 768;         // [2304][768] bf16
    u16* Wprojt = Wqkvt + (size_t)2304 * 768;     // [768][768] bf16
    u16* attn16 = qkv_raw;                   // alias: raw dead after pooling
    float* out = (float*)d_out;

    // 0) converts / transposes
    cvt_f32_to_bf16<<<(M_ * 768 / 4 + 255) / 256, 256, 0, stream>>>(x, x16, M_ * 768 / 4);
    transpose_cvt<<<dim3(2304 / 32, 768 / 32), 256, 0, stream>>>(Wqkv, Wqkvt, 2304);
    transpose_cvt<<<dim3(768 / 32, 768 / 32), 256, 0, stream>>>(Wproj, Wprojt, 768);

    // 1) qkv GEMM (bf16 MFMA) with bf16 scatter into q/k/v [B][NH][N][D]
    gemm_bf16_kernel<2304, true><<<dim3(18, 99), 256, 0, stream>>>(x16, Wqkvt, bqkv, qkv_raw);

    // 2) zero padded buffers (covers pad rows), then pool + LN
    const size_t bf16_total = ((size_t)64 * QPAD * 96 + 2 * (size_t)64 * KPAD * 96) * 2;
    hipMemsetAsync(q16, 0, bf16_total, stream);
    pool_ln_row_kernel<1, 14, 14><<<dim3(29, 64), 256, 0, stream>>>(
        qkv_raw, cwq, lnqg, lnqb, q16, QPAD, SCALE_);
    pool_ln_row_kernel<2, 7, 7><<<dim3(15, 64), 256, 0, stream>>>(
        qkv_raw + QKV1, cwk, lnkg, lnkb, k16, KPAD, 1.f);
    pool_ln_row_kernel<2, 7, 7><<<dim3(15, 64), 256, 0, stream>>>(
        qkv_raw + 2 * QKV1, cwv, lnvg, lnvb, v16, KPAD, 1.f);

    // 3) MFMA attention -> bf16 [M_][768]
    attn_mfma_kernel<<<dim3(25, 64), 256, 0, stream>>>(q16, k16, v16, attn16);

    // 4) output projection (bf16 MFMA) -> fp32 d_out
    gemm_bf16_kernel<768, false><<<dim3(6, 99), 256, 0, stream>>>(attn16, Wprojt, bproj, out);
}

// Round 5
// 332.260 us; speedup vs baseline: 17.4210x; 1.0826x over previous
//
#include <hip/hip_runtime.h>
#include <hip/hip_bf16.h>
#include <math.h>

#define B_   8
#define NH_  8
#define D_   96
#define C_   768
#define N_   1569          // 8*14*14 + 1
#define NKV_ 393           // 8*7*7 + 1
#define M_   (B_*N_)       // 12552
#define QKV1 ((size_t)B_*NH_*N_*D_)    // 9,639,936 elems per tensor
#define QPAD 1600          // padded q rows per slab (25 tiles of 64)
#define KPAD 416           // padded kv rows per slab (13 tiles of 32)
#define SCALE_ 0.10206207261596575f    // 96^-0.5

using short8v = __attribute__((ext_vector_type(8))) short;
using f32x4   = __attribute__((ext_vector_type(4))) float;
typedef unsigned short u16;

#define GLOAD_LDS16(g, l) __builtin_amdgcn_global_load_lds( \
    (const __attribute__((address_space(1))) void*)(g),     \
    (__attribute__((address_space(3))) void*)(l), 16, 0, 0)

static __device__ __forceinline__ u16 f2bf(float f) {
    __hip_bfloat16 b = __float2bfloat16(f);
    return *(u16*)&b;
}
static __device__ __forceinline__ float bf2f(u16 v) {
    return __bfloat162float(*(const __hip_bfloat16*)&v);
}

// bijective XCD swizzle (m204): consecutive swizzled ids land on one XCD
static __device__ __forceinline__ unsigned xcd_swizzle(unsigned orig, unsigned nwg) {
    const unsigned qq = nwg >> 3, rr = nwg & 7;
    const unsigned xcd = orig & 7, loc = orig >> 3;
    return (xcd < rr ? xcd * (qq + 1) : rr * (qq + 1) + (xcd - rr) * qq) + loc;
}

// ---------------------------------------------------------------------------
// fp32 -> bf16 flat convert (n4 float4 chunks)
// ---------------------------------------------------------------------------
__global__ __launch_bounds__(256)
void cvt_f32_to_bf16(const float* __restrict__ in, u16* __restrict__ out, int n4)
{
    const int i = blockIdx.x * 256 + threadIdx.x;
    if (i < n4) {
        const float4 v = ((const float4*)in)[i];
        ushort4 o;
        o.x = f2bf(v.x); o.y = f2bf(v.y); o.z = f2bf(v.z); o.w = f2bf(v.w);
        ((ushort4*)out)[i] = o;
    }
}

// ---------------------------------------------------------------------------
// W [768][ncols] fp32  ->  Wt [ncols][768] bf16   (32x32 LDS tiles)
// ---------------------------------------------------------------------------
__global__ __launch_bounds__(256)
void transpose_cvt(const float* __restrict__ W, u16* __restrict__ Wt, int ncols)
{
    __shared__ float tile[32][33];
    const int tx = threadIdx.x & 31, ty = threadIdx.x >> 5;   // 32 x 8
    const int n0 = blockIdx.x * 32, k0 = blockIdx.y * 32;
    #pragma unroll
    for (int i = 0; i < 4; ++i)
        tile[ty + i * 8][tx] = W[(size_t)(k0 + ty + i * 8) * ncols + n0 + tx];
    __syncthreads();
    #pragma unroll
    for (int i = 0; i < 4; ++i)
        Wt[(size_t)(n0 + ty + i * 8) * 768 + k0 + tx] = f2bf(tile[tx][ty + i * 8]);
}

// ---------------------------------------------------------------------------
// zero V^T pad columns (j in [NKV_, KPAD)) — required finite for PV MFMA
// ---------------------------------------------------------------------------
__global__ __launch_bounds__(256)
void zero_pad_vt(u16* __restrict__ vt)
{
    const int i = blockIdx.x * 256 + threadIdx.x;
    const int total = 64 * 96 * (KPAD - NKV_);
    if (i < total) {
        const int j = i % (KPAD - NKV_);
        const int rest = i / (KPAD - NKV_);     // slab*96 + d
        vt[(size_t)rest * KPAD + NKV_ + j] = 0;
    }
}

// ---------------------------------------------------------------------------
// bf16 MFMA GEMM, double-buffered: out = A[M_ x 768] * Bt[NC x 768]^T + bias.
// 1-D grid with XCD swizzle. Prefetch next K-tile before computing current;
// one vmcnt+barrier per K-step.
// ---------------------------------------------------------------------------
template<int NC, bool SCATTER>
__global__ __launch_bounds__(256)
void gemm_bf16_kernel(const u16* __restrict__ A, const u16* __restrict__ Bt,
                      const float* __restrict__ bias, void* __restrict__ outp)
{
    constexpr int NXT = NC / 128;
    __shared__ alignas(16) u16 As[2][128 * 64];
    __shared__ alignas(16) u16 Bs[2][128 * 64];

    const int tid  = threadIdx.x;
    const int w    = tid >> 6, lane = tid & 63;
    const int c    = lane & 15, g = lane >> 4;
    const int wm   = w >> 1, wn = w & 1;
    const int lrow = lane >> 3, lcol = lane & 7;

    const unsigned wg = xcd_swizzle(blockIdx.x, gridDim.x);
    const int m0 = (int)(wg / NXT) * 128;
    const int n0 = (int)(wg % NXT) * 128;

    f32x4 acc[4][4];
    #pragma unroll
    for (int i = 0; i < 4; ++i)
        #pragma unroll
        for (int j = 0; j < 4; ++j) acc[i][j] = (f32x4){0.f, 0.f, 0.f, 0.f};

#define STAGE(BUF, K0) do {                                                      \
    _Pragma("unroll")                                                            \
    for (int t = 0; t < 4; ++t) {                                                \
        const int r = t * 32 + w * 8;                                            \
        int m = m0 + r + lrow; if (m >= M_) m = M_ - 1;                          \
        GLOAD_LDS16(&A[(size_t)m * 768 + (K0) + lcol * 8], &As[BUF][r * 64]);    \
        GLOAD_LDS16(&Bt[(size_t)(n0 + r + lrow) * 768 + (K0) + lcol * 8],        \
                    &Bs[BUF][r * 64]);                                           \
    } } while (0)

#define COMPUTE(BUF) do {                                                        \
    _Pragma("unroll")                                                            \
    for (int kk = 0; kk < 2; ++kk) {                                             \
        short8v a[4], b[4];                                                      \
        _Pragma("unroll")                                                        \
        for (int i = 0; i < 4; ++i) {                                            \
            a[i] = *(const short8v*)&As[BUF][(wm*64 + i*16 + c)*64 + kk*32 + g*8]; \
            b[i] = *(const short8v*)&Bs[BUF][(wn*64 + i*16 + c)*64 + kk*32 + g*8]; \
        }                                                                        \
        _Pragma("unroll")                                                        \
        for (int i = 0; i < 4; ++i)                                              \
            _Pragma("unroll")                                                    \
            for (int j = 0; j < 4; ++j)                                          \
                acc[i][j] = __builtin_amdgcn_mfma_f32_16x16x32_bf16(             \
                    a[i], b[j], acc[i][j], 0, 0, 0);                             \
    } } while (0)

    STAGE(0, 0);
    __syncthreads();                       // compiler drains vmcnt before barrier
    #pragma unroll
    for (int tt = 0; tt < 6; ++tt) {
        const int t0 = tt * 2;
        STAGE(1, (t0 + 1) * 64);           // prefetch odd tile
        COMPUTE(0);
        __syncthreads();
        if (t0 + 2 < 12) STAGE(0, (t0 + 2) * 64);   // prefetch next even tile
        COMPUTE(1);
        if (t0 + 2 < 12) __syncthreads();
    }
#undef STAGE
#undef COMPUTE

    #pragma unroll
    for (int i = 0; i < 4; ++i) {
        const int mrow = m0 + wm * 64 + i * 16 + g * 4;
        #pragma unroll
        for (int j = 0; j < 4; ++j) {
            const int ncol = n0 + wn * 64 + j * 16 + c;
            const float bv = bias[ncol];
            if constexpr (SCATTER) {
                u16* out = (u16*)outp;
                const int s   = ncol / C_;          // 0=q,1=k,2=v
                const int rem = ncol - s * C_;
                const int hh  = rem / D_;
                const int dd  = rem - hh * D_;
                #pragma unroll
                for (int r = 0; r < 4; ++r) {
                    const int m = mrow + r;
                    if (m < M_) {
                        const int bb2 = m / N_;
                        const int n = m - bb2 * N_;
                        out[(size_t)s * QKV1 +
                            ((size_t)(bb2 * NH_ + hh) * N_ + n) * D_ + dd] = f2bf(acc[i][j][r] + bv);
                    }
                }
            } else {
                float* out = (float*)outp;
                #pragma unroll
                for (int r = 0; r < 4; ++r) {
                    const int m = mrow + r;
                    if (m < M_) out[(size_t)m * NC + ncol] = acc[i][j][r] + bv;
                }
            }
        }
    }
}

// ---------------------------------------------------------------------------
// Row-per-wave depthwise 3x3x3 pool + LayerNorm (bf16 in/out, f32 math).
// VT=false: out[bh][tok][96].  VT=true: out[bh][96][KPAD] (transposed).
// ---------------------------------------------------------------------------
template<int STRIDE, int OH, int OW, bool VT>
static __device__ __forceinline__
void pool_ln_body(const u16* __restrict__ in, const float* __restrict__ wsm,
                  const float* __restrict__ g, const float* __restrict__ bta,
                  u16* __restrict__ out, int tokstride, float oscale,
                  int bh, int R)
{
    const int lane = threadIdx.x & 63;
    const int NROWS = 8 * OH;
    if (R > NROWS) return;

    const bool hi = lane < 32;
    const size_t inbase = (size_t)bh * N_ * 96;
    const int ch0 = lane, ch1 = 64 + (lane & 31);
    const float g0 = g[ch0], b0 = bta[ch0];
    const float g1 = g[ch1], b1 = bta[ch1];
    const size_t obase = (size_t)bh * tokstride * 96;

    if (R == NROWS) {   // cls token: LN only
        float v0 = bf2f(in[inbase + ch0]);
        float v1 = bf2f(in[inbase + ch1]);
        float s = v0 + (hi ? v1 : 0.f);
        #pragma unroll
        for (int off = 32; off; off >>= 1) s += __shfl_xor(s, off, 64);
        float sq = v0 * v0 + (hi ? v1 * v1 : 0.f);
        #pragma unroll
        for (int off = 32; off; off >>= 1) sq += __shfl_xor(sq, off, 64);
        const float mu = s * (1.f / 96.f);
        const float rstd = rsqrtf(sq * (1.f / 96.f) - mu * mu + 1e-5f);
        const float y0 = ((v0 - mu) * rstd * g0 + b0) * oscale;
        const float y1 = ((v1 - mu) * rstd * g1 + b1) * oscale;
        if constexpr (VT) {
            out[obase + (size_t)ch0 * KPAD] = f2bf(y0);
            if (hi) out[obase + (size_t)ch1 * KPAD] = f2bf(y1);
        } else {
            out[obase + ch0] = f2bf(y0);
            if (hi) out[obase + ch1] = f2bf(y1);
        }
        return;
    }

    const int to = R / OH, ho = R % OH;
    float a0[OW], a1[OW];
    #pragma unroll
    for (int wo = 0; wo < OW; ++wo) { a0[wo] = 0.f; a1[wo] = 0.f; }

    for (int dt = 0; dt < 3; ++dt) {
        const int t = to - 1 + dt;
        if (t < 0 || t >= 8) continue;
        for (int dh = 0; dh < 3; ++dh) {
            const int h = ho * STRIDE - 1 + dh;
            if (h < 0 || h >= 14) continue;
            float x0[14], x1[14];
            #pragma unroll
            for (int iw = 0; iw < 14; ++iw) {
                const size_t tin = inbase + (size_t)(1 + (t * 14 + h) * 14 + iw) * 96;
                x0[iw] = bf2f(in[tin + ch0]);
                x1[iw] = bf2f(in[tin + ch1]);
            }
            const int tapb = dt * 9 + dh * 3;
            float wt0[3], wt1[3];
            #pragma unroll
            for (int dw = 0; dw < 3; ++dw) {
                wt0[dw] = wsm[ch0 * 27 + tapb + dw];
                wt1[dw] = wsm[ch1 * 27 + tapb + dw];
            }
            #pragma unroll
            for (int wo = 0; wo < OW; ++wo)
                #pragma unroll
                for (int dw = 0; dw < 3; ++dw) {
                    const int iw = wo * STRIDE - 1 + dw;
                    if (iw < 0 || iw >= 14) continue;   // compile-time
                    a0[wo] += wt0[dw] * x0[iw];
                    a1[wo] += wt1[dw] * x1[iw];
                }
        }
    }

    #pragma unroll
    for (int wo = 0; wo < OW; ++wo) {
        float s = a0[wo] + (hi ? a1[wo] : 0.f);
        #pragma unroll
        for (int off = 32; off; off >>= 1) s += __shfl_xor(s, off, 64);
        float sq = a0[wo] * a0[wo] + (hi ? a1[wo] * a1[wo] : 0.f);
        #pragma unroll
        for (int off = 32; off; off >>= 1) sq += __shfl_xor(sq, off, 64);
        const float mu = s * (1.f / 96.f);
        const float rstd = rsqrtf(sq * (1.f / 96.f) - mu * mu + 1e-5f);
        const int tok = 1 + (to * OH + ho) * OW + wo;
        const float y0 = ((a0[wo] - mu) * rstd * g0 + b0) * oscale;
        const float y1 = ((a1[wo] - mu) * rstd * g1 + b1) * oscale;
        if constexpr (VT) {
            out[obase + (size_t)ch0 * KPAD + tok] = f2bf(y0);
            if (hi) out[obase + (size_t)ch1 * KPAD + tok] = f2bf(y1);
        } else {
            out[obase + (size_t)tok * 96 + ch0] = f2bf(y0);
            if (hi) out[obase + (size_t)tok * 96 + ch1] = f2bf(y1);
        }
    }
}

__global__ __launch_bounds__(256)
void pool_ln_q_kernel(const u16* __restrict__ in, const float* __restrict__ cw,
                      const float* __restrict__ g, const float* __restrict__ bta,
                      u16* __restrict__ out)
{
    __shared__ float wsm[96 * 27];
    for (int i = threadIdx.x; i < 96 * 27; i += 256) wsm[i] = cw[i];
    __syncthreads();
    const int w = threadIdx.x >> 6;
    pool_ln_body<1, 14, 14, false>(in, wsm, g, bta, out, QPAD, SCALE_,
                                   blockIdx.y, blockIdx.x * 4 + w);
}

// fused k (normal layout) + v (transposed layout): grid.y in [0,128)
__global__ __launch_bounds__(256)
void pool_ln_kv_kernel(const u16* __restrict__ kin, const float* __restrict__ cwk,
                       const float* __restrict__ gk, const float* __restrict__ bk,
                       u16* __restrict__ kout,
                       const u16* __restrict__ vin, const float* __restrict__ cwv,
                       const float* __restrict__ gv, const float* __restrict__ bv,
                       u16* __restrict__ vout)
{
    __shared__ float wsm[96 * 27];
    const bool isv = blockIdx.y >= 64;
    const float* cw = isv ? cwv : cwk;
    for (int i = threadIdx.x; i < 96 * 27; i += 256) wsm[i] = cw[i];
    __syncthreads();
    const int w = threadIdx.x >> 6;
    const int bh = blockIdx.y & 63;
    const int R = blockIdx.x * 4 + w;
    if (isv)
        pool_ln_body<2, 7, 7, true >(vin, wsm, gv, bv, vout, KPAD, 1.f, bh, R);
    else
        pool_ln_body<2, 7, 7, false>(kin, wsm, gk, bk, kout, KPAD, 1.f, bh, R);
}

// ---------------------------------------------------------------------------
// MFMA attention -> bf16 [M_][768]. Q pre-scaled. V is transposed [96][KPAD].
// 1-D grid (1600) with XCD swizzle: 8 consecutive-bh slabs per XCD chunk.
// ---------------------------------------------------------------------------
__global__ __launch_bounds__(256)
void attn_mfma_kernel(const u16* __restrict__ Q, const u16* __restrict__ K,
                      const u16* __restrict__ VT, u16* __restrict__ Out)
{
    __shared__ alignas(16) u16 plds[4][512];   // per-wave 16x32 bf16 P tile
    const int tid  = threadIdx.x;
    const int w    = tid >> 6, lane = tid & 63;
    const int c    = lane & 15, g = lane >> 4;

    const unsigned wg = xcd_swizzle(blockIdx.x, gridDim.x);
    const int bh = (int)(wg / 25);
    const int b  = bh >> 3, hh = bh & 7;
    const int q0 = (int)(wg % 25) * 64 + w * 16;
    const int qrow = q0 + c;

    const size_t qbase = (size_t)bh * QPAD * 96;
    const size_t kbase = (size_t)bh * KPAD * 96;   // K rows / VT elems both 96*KPAD per slab

    short8v qa[3];
    #pragma unroll
    for (int kf = 0; kf < 3; ++kf)
        qa[kf] = *(const short8v*)&Q[qbase + (size_t)qrow * 96 + kf * 32 + g * 8];

    f32x4 oacc[6];
    #pragma unroll
    for (int t = 0; t < 6; ++t) oacc[t] = (f32x4){0.f, 0.f, 0.f, 0.f};
    float lsum[4] = {0.f, 0.f, 0.f, 0.f};

    for (int pr = 0; pr < 13; ++pr) {
        #pragma unroll
        for (int h = 0; h < 2; ++h) {
            const int jcol = pr * 32 + h * 16 + c;
            const u16* kp = &K[kbase + (size_t)jcol * 96 + g * 8];
            short8v kb0 = *(const short8v*)&kp[0];
            short8v kb1 = *(const short8v*)&kp[32];
            short8v kb2 = *(const short8v*)&kp[64];
            f32x4 sacc = (f32x4){0.f, 0.f, 0.f, 0.f};
            sacc = __builtin_amdgcn_mfma_f32_16x16x32_bf16(qa[0], kb0, sacc, 0, 0, 0);
            sacc = __builtin_amdgcn_mfma_f32_16x16x32_bf16(qa[1], kb1, sacc, 0, 0, 0);
            sacc = __builtin_amdgcn_mfma_f32_16x16x32_bf16(qa[2], kb2, sacc, 0, 0, 0);
            #pragma unroll
            for (int r = 0; r < 4; ++r) {
                float s = sacc[r];
                if (jcol >= NKV_) s = -1e30f;
                const float p = __expf(s);
                lsum[r] += p;
                const int q    = g * 4 + r;
                const int j    = h * 16 + c;
                const int dstL = q | ((j >> 3) << 4);
                plds[w][dstL * 8 + (j & 7)] = f2bf(p);
            }
        }
        asm volatile("s_waitcnt lgkmcnt(0)" ::: "memory");
        const short8v pa = *(const short8v*)&plds[w][lane * 8];

        #pragma unroll
        for (int t = 0; t < 6; ++t) {
            const int d0 = t * 16;
            const short8v vb = *(const short8v*)
                &VT[kbase + (size_t)(d0 + c) * KPAD + pr * 32 + g * 8];
            oacc[t] = __builtin_amdgcn_mfma_f32_16x16x32_bf16(pa, vb, oacc[t], 0, 0, 0);
        }
    }

    float linv[4];
    #pragma unroll
    for (int r = 0; r < 4; ++r) {
        float s = lsum[r];
        s += __shfl_xor(s, 1, 64);
        s += __shfl_xor(s, 2, 64);
        s += __shfl_xor(s, 4, 64);
        s += __shfl_xor(s, 8, 64);
        linv[r] = 1.f / s;
    }

    #pragma unroll
    for (int t = 0; t < 6; ++t)
        #pragma unroll
        for (int r = 0; r < 4; ++r) {
            const int row = q0 + g * 4 + r;
            if (row < N_)
                Out[((size_t)(b * N_ + row)) * 768 + hh * 96 + t * 16 + c] =
                    f2bf(oacc[t][r] * linv[r]);
        }
}

// ---------------------------------------------------------------------------
extern "C" void kernel_launch(void* const* d_in, const int* in_sizes, int n_in,
                              void* d_out, int out_size, void* d_ws, size_t ws_size,
                              hipStream_t stream)
{
    const float* x     = (const float*)d_in[0];
    const float* Wqkv  = (const float*)d_in[1];
    const float* bqkv  = (const float*)d_in[2];
    const float* Wproj = (const float*)d_in[3];
    const float* bproj = (const float*)d_in[4];
    const float* cwq   = (const float*)d_in[5];
    const float* cwk   = (const float*)d_in[6];
    const float* cwv   = (const float*)d_in[7];
    const float* lnqg  = (const float*)d_in[8];
    const float* lnqb  = (const float*)d_in[9];
    const float* lnkg  = (const float*)d_in[10];
    const float* lnkb  = (const float*)d_in[11];
    const float* lnvg  = (const float*)d_in[12];
    const float* lnvb  = (const float*)d_in[13];

    u16* ws = (u16*)d_ws;
    u16* qkv_raw = ws;                       // 3 x [B][NH][N][D] bf16
    u16* q16 = qkv_raw + 3 * QKV1;           // [64][QPAD][96]
    u16* k16 = q16 + (size_t)64 * QPAD * 96; // [64][KPAD][96]
    u16* vt16 = k16 + (size_t)64 * KPAD * 96;// [64][96][KPAD] (transposed)
    u16* x16    = vt16 + (size_t)64 * KPAD * 96;  // [12552][768]
    u16* Wqkvt  = x16 + (size_t)M_ * 768;         // [2304][768]
    u16* Wprojt = Wqkvt + (size_t)2304 * 768;     // [768][768]
    u16* attn16 = qkv_raw;                   // alias: raw dead after pooling
    float* out = (float*)d_out;

    // 0) converts / transposes / VT pad zero
    cvt_f32_to_bf16<<<(M_ * 768 / 4 + 255) / 256, 256, 0, stream>>>(x, x16, M_ * 768 / 4);
    transpose_cvt<<<dim3(2304 / 32, 768 / 32), 256, 0, stream>>>(Wqkv, Wqkvt, 2304);
    transpose_cvt<<<dim3(768 / 32, 768 / 32), 256, 0, stream>>>(Wproj, Wprojt, 768);
    zero_pad_vt<<<(64 * 96 * (KPAD - NKV_) + 255) / 256, 256, 0, stream>>>(vt16);

    // 1) qkv GEMM (dbuf MFMA) with bf16 scatter into q/k/v [B][NH][N][D]
    gemm_bf16_kernel<2304, true><<<18 * 99, 256, 0, stream>>>(x16, Wqkvt, bqkv, qkv_raw);

    // 2) pool + LN (q normal; k normal; v transposed)
    pool_ln_q_kernel<<<dim3(29, 64), 256, 0, stream>>>(qkv_raw, cwq, lnqg, lnqb, q16);
    pool_ln_kv_kernel<<<dim3(15, 128), 256, 0, stream>>>(
        qkv_raw + QKV1, cwk, lnkg, lnkb, k16,
        qkv_raw + 2 * QKV1, cwv, lnvg, lnvb, vt16);

    // 3) MFMA attention -> bf16 [M_][768]
    attn_mfma_kernel<<<25 * 64, 256, 0, stream>>>(q16, k16, vt16, attn16);

    // 4) output projection (dbuf MFMA) -> fp32 d_out
    gemm_bf16_kernel<768, false><<<6 * 99, 256, 0, stream>>>(attn16, Wprojt, bproj, out);
}

// Round 6
// 302.844 us; speedup vs baseline: 19.1131x; 1.0971x over previous
//
#include <hip/hip_runtime.h>
#include <hip/hip_bf16.h>
#include <math.h>

#define B_   8
#define NH_  8
#define D_   96
#define C_   768
#define N_   1569          // 8*14*14 + 1
#define NKV_ 393           // 8*7*7 + 1
#define M_   (B_*N_)       // 12552
#define QKV1 ((size_t)B_*NH_*N_*D_)    // 9,639,936 elems per tensor
#define QPAD 1600          // padded q rows per slab (25 tiles of 64)
#define KPAD 416           // padded kv rows per slab (13 tiles of 32)
#define SCALE_ 0.10206207261596575f    // 96^-0.5

using short8v = __attribute__((ext_vector_type(8))) short;
using f32x4   = __attribute__((ext_vector_type(4))) float;
typedef unsigned short u16;

#define GLOAD_LDS16(g, l) __builtin_amdgcn_global_load_lds( \
    (const __attribute__((address_space(1))) void*)(g),     \
    (__attribute__((address_space(3))) void*)(l), 16, 0, 0)

static __device__ __forceinline__ u16 f2bf(float f) {
    __hip_bfloat16 b = __float2bfloat16(f);
    return *(u16*)&b;
}
static __device__ __forceinline__ float bf2f(u16 v) {
    return __bfloat162float(*(const __hip_bfloat16*)&v);
}

// bijective XCD swizzle (m204): consecutive swizzled ids land on one XCD
static __device__ __forceinline__ unsigned xcd_swizzle(unsigned orig, unsigned nwg) {
    const unsigned qq = nwg >> 3, rr = nwg & 7;
    const unsigned xcd = orig & 7, loc = orig >> 3;
    return (xcd < rr ? xcd * (qq + 1) : rr * (qq + 1) + (xcd - rr) * qq) + loc;
}

// ---------------------------------------------------------------------------
// fp32 -> bf16 flat convert (n4 float4 chunks)
// ---------------------------------------------------------------------------
__global__ __launch_bounds__(256)
void cvt_f32_to_bf16(const float* __restrict__ in, u16* __restrict__ out, int n4)
{
    const int i = blockIdx.x * 256 + threadIdx.x;
    if (i < n4) {
        const float4 v = ((const float4*)in)[i];
        ushort4 o;
        o.x = f2bf(v.x); o.y = f2bf(v.y); o.z = f2bf(v.z); o.w = f2bf(v.w);
        ((ushort4*)out)[i] = o;
    }
}

// ---------------------------------------------------------------------------
// W [768][ncols] fp32  ->  Wt [ncols][768] bf16   (32x32 LDS tiles)
// ---------------------------------------------------------------------------
__global__ __launch_bounds__(256)
void transpose_cvt(const float* __restrict__ W, u16* __restrict__ Wt, int ncols)
{
    __shared__ float tile[32][33];
    const int tx = threadIdx.x & 31, ty = threadIdx.x >> 5;   // 32 x 8
    const int n0 = blockIdx.x * 32, k0 = blockIdx.y * 32;
    #pragma unroll
    for (int i = 0; i < 4; ++i)
        tile[ty + i * 8][tx] = W[(size_t)(k0 + ty + i * 8) * ncols + n0 + tx];
    __syncthreads();
    #pragma unroll
    for (int i = 0; i < 4; ++i)
        Wt[(size_t)(n0 + ty + i * 8) * 768 + k0 + tx] = f2bf(tile[tx][ty + i * 8]);
}

// ---------------------------------------------------------------------------
// zero V^T pad columns (j in [NKV_, KPAD)) — required finite for PV MFMA
// ---------------------------------------------------------------------------
__global__ __launch_bounds__(256)
void zero_pad_vt(u16* __restrict__ vt)
{
    const int i = blockIdx.x * 256 + threadIdx.x;
    const int total = 64 * 96 * (KPAD - NKV_);
    if (i < total) {
        const int j = i % (KPAD - NKV_);
        const int rest = i / (KPAD - NKV_);     // slab*96 + d
        vt[(size_t)rest * KPAD + NKV_ + j] = 0;
    }
}

// ---------------------------------------------------------------------------
// bf16 MFMA GEMM, counted-vmcnt pipeline (T3+T4) + LDS XOR swizzle (T2).
// out = A[M_ x 768] * Bt[NC x 768]^T + bias. 1-D grid with XCD swizzle.
// Per K-step: vmcnt(8) (keep next tile's 8 loads in flight) -> barrier ->
// ds_read all frags -> lgkmcnt(0)+barrier -> prefetch t+2 into this buf ->
// 32 MFMAs. LDS physical col16 = logical col16 ^ (row & 7), both sides.
// ---------------------------------------------------------------------------
template<int NC, bool SCATTER>
__global__ __launch_bounds__(256)
void gemm_bf16_kernel(const u16* __restrict__ A, const u16* __restrict__ Bt,
                      const float* __restrict__ bias, void* __restrict__ outp)
{
    constexpr int NXT = NC / 128;
    __shared__ alignas(16) u16 As[2][128 * 64];
    __shared__ alignas(16) u16 Bs[2][128 * 64];

    const int tid  = threadIdx.x;
    const int w    = tid >> 6, lane = tid & 63;
    const int c    = lane & 15, g = lane >> 4;
    const int wm   = w >> 1, wn = w & 1;
    const int lrow = lane >> 3, lcol = lane & 7;

    const unsigned wg = xcd_swizzle(blockIdx.x, gridDim.x);
    const int m0 = (int)(wg / NXT) * 128;
    const int n0 = (int)(wg % NXT) * 128;

    f32x4 acc[4][4];
    #pragma unroll
    for (int i = 0; i < 4; ++i)
        #pragma unroll
        for (int j = 0; j < 4; ++j) acc[i][j] = (f32x4){0.f, 0.f, 0.f, 0.f};

    // swizzled stage: lane's fixed LDS slot (row, col16=lcol) receives
    // global col16 (lcol ^ (row&7))  [involution with the read-side XOR]
#define STAGE(BUF, K0) do {                                                      \
    _Pragma("unroll")                                                            \
    for (int t = 0; t < 4; ++t) {                                                \
        const int r = t * 32 + w * 8;                                            \
        const int row = r + lrow;                                                \
        const int scol = (lcol ^ (row & 7)) * 8;                                 \
        int m = m0 + row; if (m >= M_) m = M_ - 1;                               \
        GLOAD_LDS16(&A[(size_t)m * 768 + (K0) + scol], &As[BUF][r * 64]);        \
        GLOAD_LDS16(&Bt[(size_t)(n0 + row) * 768 + (K0) + scol],                 \
                    &Bs[BUF][r * 64]);                                           \
    } } while (0)

    const int xora = (g ^ (c & 7)) * 8;          // kk=0: logical col16 = g
    const int xorb = ((4 + g) ^ (c & 7)) * 8;    // kk=1: logical col16 = 4+g

#define KSTEP(BUF, LAST, PREF, KNEXT) do {                                       \
    if (LAST) asm volatile("s_waitcnt vmcnt(0)" ::: "memory");                   \
    else      asm volatile("s_waitcnt vmcnt(8)" ::: "memory");                   \
    __builtin_amdgcn_s_barrier();                                                \
    short8v a0[4], a1[4], b0[4], b1[4];                                          \
    _Pragma("unroll")                                                            \
    for (int i = 0; i < 4; ++i) {                                                \
        const int ra = (wm * 64 + i * 16 + c) * 64;                              \
        const int rb = (wn * 64 + i * 16 + c) * 64;                              \
        a0[i] = *(const short8v*)&As[BUF][ra + xora];                            \
        a1[i] = *(const short8v*)&As[BUF][ra + xorb];                            \
        b0[i] = *(const short8v*)&Bs[BUF][rb + xora];                            \
        b1[i] = *(const short8v*)&Bs[BUF][rb + xorb];                            \
    }                                                                            \
    asm volatile("s_waitcnt lgkmcnt(0)" ::: "memory");                           \
    __builtin_amdgcn_sched_barrier(0);                                           \
    __builtin_amdgcn_s_barrier();                                                \
    if (PREF) STAGE(BUF, KNEXT);                                                 \
    _Pragma("unroll")                                                            \
    for (int i = 0; i < 4; ++i)                                                  \
        _Pragma("unroll")                                                        \
        for (int j = 0; j < 4; ++j)                                              \
            acc[i][j] = __builtin_amdgcn_mfma_f32_16x16x32_bf16(                 \
                a0[i], b0[j], acc[i][j], 0, 0, 0);                               \
    _Pragma("unroll")                                                            \
    for (int i = 0; i < 4; ++i)                                                  \
        _Pragma("unroll")                                                        \
        for (int j = 0; j < 4; ++j)                                              \
            acc[i][j] = __builtin_amdgcn_mfma_f32_16x16x32_bf16(                 \
                a1[i], b1[j], acc[i][j], 0, 0, 0);                               \
    } while (0)

    STAGE(0, 0);
    STAGE(1, 64);
    #pragma unroll
    for (int tt = 0; tt < 5; ++tt) {
        KSTEP(0, false, true, (2 * tt + 2) * 64);
        KSTEP(1, false, true, (2 * tt + 3) * 64);
    }
    KSTEP(0, false, false, 0);    // t=10: t=11 still in flight
    KSTEP(1, true,  false, 0);    // t=11: drain
#undef STAGE
#undef KSTEP

    #pragma unroll
    for (int i = 0; i < 4; ++i) {
        const int mrow = m0 + wm * 64 + i * 16 + g * 4;
        #pragma unroll
        for (int j = 0; j < 4; ++j) {
            const int ncol = n0 + wn * 64 + j * 16 + c;
            const float bv = bias[ncol];
            if constexpr (SCATTER) {
                u16* out = (u16*)outp;
                const int s   = ncol / C_;          // 0=q,1=k,2=v
                const int rem = ncol - s * C_;
                const int hh  = rem / D_;
                const int dd  = rem - hh * D_;
                #pragma unroll
                for (int r = 0; r < 4; ++r) {
                    const int m = mrow + r;
                    if (m < M_) {
                        const int bb2 = m / N_;
                        const int n = m - bb2 * N_;
                        out[(size_t)s * QKV1 +
                            ((size_t)(bb2 * NH_ + hh) * N_ + n) * D_ + dd] = f2bf(acc[i][j][r] + bv);
                    }
                }
            } else {
                float* out = (float*)outp;
                #pragma unroll
                for (int r = 0; r < 4; ++r) {
                    const int m = mrow + r;
                    if (m < M_) out[(size_t)m * NC + ncol] = acc[i][j][r] + bv;
                }
            }
        }
    }
}

// ---------------------------------------------------------------------------
// Row-per-wave depthwise 3x3x3 pool + LayerNorm (bf16 in/out, f32 math).
// VT=false: out[bh][tok][96].  VT=true: out[bh][96][KPAD] (transposed).
// ---------------------------------------------------------------------------
template<int STRIDE, int OH, int OW, bool VT>
static __device__ __forceinline__
void pool_ln_body(const u16* __restrict__ in, const float* __restrict__ wsm,
                  const float* __restrict__ g, const float* __restrict__ bta,
                  u16* __restrict__ out, int tokstride, float oscale,
                  int bh, int R)
{
    const int lane = threadIdx.x & 63;
    const int NROWS = 8 * OH;
    if (R > NROWS) return;

    const bool hi = lane < 32;
    const size_t inbase = (size_t)bh * N_ * 96;
    const int ch0 = lane, ch1 = 64 + (lane & 31);
    const float g0 = g[ch0], b0 = bta[ch0];
    const float g1 = g[ch1], b1 = bta[ch1];
    const size_t obase = (size_t)bh * tokstride * 96;

    if (R == NROWS) {   // cls token: LN only
        float v0 = bf2f(in[inbase + ch0]);
        float v1 = bf2f(in[inbase + ch1]);
        float s = v0 + (hi ? v1 : 0.f);
        #pragma unroll
        for (int off = 32; off; off >>= 1) s += __shfl_xor(s, off, 64);
        float sq = v0 * v0 + (hi ? v1 * v1 : 0.f);
        #pragma unroll
        for (int off = 32; off; off >>= 1) sq += __shfl_xor(sq, off, 64);
        const float mu = s * (1.f / 96.f);
        const float rstd = rsqrtf(sq * (1.f / 96.f) - mu * mu + 1e-5f);
        const float y0 = ((v0 - mu) * rstd * g0 + b0) * oscale;
        const float y1 = ((v1 - mu) * rstd * g1 + b1) * oscale;
        if constexpr (VT) {
            out[obase + (size_t)ch0 * KPAD] = f2bf(y0);
            if (hi) out[obase + (size_t)ch1 * KPAD] = f2bf(y1);
        } else {
            out[obase + ch0] = f2bf(y0);
            if (hi) out[obase + ch1] = f2bf(y1);
        }
        return;
    }

    const int to = R / OH, ho = R % OH;
    float a0[OW], a1[OW];
    #pragma unroll
    for (int wo = 0; wo < OW; ++wo) { a0[wo] = 0.f; a1[wo] = 0.f; }

    for (int dt = 0; dt < 3; ++dt) {
        const int t = to - 1 + dt;
        if (t < 0 || t >= 8) continue;
        for (int dh = 0; dh < 3; ++dh) {
            const int h = ho * STRIDE - 1 + dh;
            if (h < 0 || h >= 14) continue;
            float x0[14], x1[14];
            #pragma unroll
            for (int iw = 0; iw < 14; ++iw) {
                const size_t tin = inbase + (size_t)(1 + (t * 14 + h) * 14 + iw) * 96;
                x0[iw] = bf2f(in[tin + ch0]);
                x1[iw] = bf2f(in[tin + ch1]);
            }
            const int tapb = dt * 9 + dh * 3;
            float wt0[3], wt1[3];
            #pragma unroll
            for (int dw = 0; dw < 3; ++dw) {
                wt0[dw] = wsm[ch0 * 27 + tapb + dw];
                wt1[dw] = wsm[ch1 * 27 + tapb + dw];
            }
            #pragma unroll
            for (int wo = 0; wo < OW; ++wo)
                #pragma unroll
                for (int dw = 0; dw < 3; ++dw) {
                    const int iw = wo * STRIDE - 1 + dw;
                    if (iw < 0 || iw >= 14) continue;   // compile-time
                    a0[wo] += wt0[dw] * x0[iw];
                    a1[wo] += wt1[dw] * x1[iw];
                }
        }
    }

    #pragma unroll
    for (int wo = 0; wo < OW; ++wo) {
        float s = a0[wo] + (hi ? a1[wo] : 0.f);
        #pragma unroll
        for (int off = 32; off; off >>= 1) s += __shfl_xor(s, off, 64);
        float sq = a0[wo] * a0[wo] + (hi ? a1[wo] * a1[wo] : 0.f);
        #pragma unroll
        for (int off = 32; off; off >>= 1) sq += __shfl_xor(sq, off, 64);
        const float mu = s * (1.f / 96.f);
        const float rstd = rsqrtf(sq * (1.f / 96.f) - mu * mu + 1e-5f);
        const int tok = 1 + (to * OH + ho) * OW + wo;
        const float y0 = ((a0[wo] - mu) * rstd * g0 + b0) * oscale;
        const float y1 = ((a1[wo] - mu) * rstd * g1 + b1) * oscale;
        if constexpr (VT) {
            out[obase + (size_t)ch0 * KPAD + tok] = f2bf(y0);
            if (hi) out[obase + (size_t)ch1 * KPAD + tok] = f2bf(y1);
        } else {
            out[obase + (size_t)tok * 96 + ch0] = f2bf(y0);
            if (hi) out[obase + (size_t)tok * 96 + ch1] = f2bf(y1);
        }
    }
}

__global__ __launch_bounds__(256)
void pool_ln_q_kernel(const u16* __restrict__ in, const float* __restrict__ cw,
                      const float* __restrict__ g, const float* __restrict__ bta,
                      u16* __restrict__ out)
{
    __shared__ float wsm[96 * 27];
    for (int i = threadIdx.x; i < 96 * 27; i += 256) wsm[i] = cw[i];
    __syncthreads();
    const int w = threadIdx.x >> 6;
    pool_ln_body<1, 14, 14, false>(in, wsm, g, bta, out, QPAD, SCALE_,
                                   blockIdx.y, blockIdx.x * 4 + w);
}

// fused k (normal layout) + v (transposed layout): grid.y in [0,128)
__global__ __launch_bounds__(256)
void pool_ln_kv_kernel(const u16* __restrict__ kin, const float* __restrict__ cwk,
                       const float* __restrict__ gk, const float* __restrict__ bk,
                       u16* __restrict__ kout,
                       const u16* __restrict__ vin, const float* __restrict__ cwv,
                       const float* __restrict__ gv, const float* __restrict__ bv,
                       u16* __restrict__ vout)
{
    __shared__ float wsm[96 * 27];
    const bool isv = blockIdx.y >= 64;
    const float* cw = isv ? cwv : cwk;
    for (int i = threadIdx.x; i < 96 * 27; i += 256) wsm[i] = cw[i];
    __syncthreads();
    const int w = threadIdx.x >> 6;
    const int bh = blockIdx.y & 63;
    const int R = blockIdx.x * 4 + w;
    if (isv)
        pool_ln_body<2, 7, 7, true >(vin, wsm, gv, bv, vout, KPAD, 1.f, bh, R);
    else
        pool_ln_body<2, 7, 7, false>(kin, wsm, gk, bk, kout, KPAD, 1.f, bh, R);
}

// ---------------------------------------------------------------------------
// MFMA attention -> bf16 [M_][768]. Q pre-scaled. V is transposed [96][KPAD].
// ---------------------------------------------------------------------------
__global__ __launch_bounds__(256)
void attn_mfma_kernel(const u16* __restrict__ Q, const u16* __restrict__ K,
                      const u16* __restrict__ VT, u16* __restrict__ Out)
{
    __shared__ alignas(16) u16 plds[4][512];   // per-wave 16x32 bf16 P tile
    const int tid  = threadIdx.x;
    const int w    = tid >> 6, lane = tid & 63;
    const int c    = lane & 15, g = lane >> 4;

    const unsigned wg = xcd_swizzle(blockIdx.x, gridDim.x);
    const int bh = (int)(wg / 25);
    const int b  = bh >> 3, hh = bh & 7;
    const int q0 = (int)(wg % 25) * 64 + w * 16;
    const int qrow = q0 + c;

    const size_t qbase = (size_t)bh * QPAD * 96;
    const size_t kbase = (size_t)bh * KPAD * 96;

    short8v qa[3];
    #pragma unroll
    for (int kf = 0; kf < 3; ++kf)
        qa[kf] = *(const short8v*)&Q[qbase + (size_t)qrow * 96 + kf * 32 + g * 8];

    f32x4 oacc[6];
    #pragma unroll
    for (int t = 0; t < 6; ++t) oacc[t] = (f32x4){0.f, 0.f, 0.f, 0.f};
    float lsum[4] = {0.f, 0.f, 0.f, 0.f};

    for (int pr = 0; pr < 13; ++pr) {
        #pragma unroll
        for (int h = 0; h < 2; ++h) {
            const int jcol = pr * 32 + h * 16 + c;
            const u16* kp = &K[kbase + (size_t)jcol * 96 + g * 8];
            short8v kb0 = *(const short8v*)&kp[0];
            short8v kb1 = *(const short8v*)&kp[32];
            short8v kb2 = *(const short8v*)&kp[64];
            f32x4 sacc = (f32x4){0.f, 0.f, 0.f, 0.f};
            sacc = __builtin_amdgcn_mfma_f32_16x16x32_bf16(qa[0], kb0, sacc, 0, 0, 0);
            sacc = __builtin_amdgcn_mfma_f32_16x16x32_bf16(qa[1], kb1, sacc, 0, 0, 0);
            sacc = __builtin_amdgcn_mfma_f32_16x16x32_bf16(qa[2], kb2, sacc, 0, 0, 0);
            #pragma unroll
            for (int r = 0; r < 4; ++r) {
                float s = sacc[r];
                if (jcol >= NKV_) s = -1e30f;
                const float p = __expf(s);
                lsum[r] += p;
                const int q    = g * 4 + r;
                const int j    = h * 16 + c;
                const int dstL = q | ((j >> 3) << 4);
                plds[w][dstL * 8 + (j & 7)] = f2bf(p);
            }
        }
        asm volatile("s_waitcnt lgkmcnt(0)" ::: "memory");
        const short8v pa = *(const short8v*)&plds[w][lane * 8];

        #pragma unroll
        for (int t = 0; t < 6; ++t) {
            const int d0 = t * 16;
            const short8v vb = *(const short8v*)
                &VT[kbase + (size_t)(d0 + c) * KPAD + pr * 32 + g * 8];
            oacc[t] = __builtin_amdgcn_mfma_f32_16x16x32_bf16(pa, vb, oacc[t], 0, 0, 0);
        }
    }

    float linv[4];
    #pragma unroll
    for (int r = 0; r < 4; ++r) {
        float s = lsum[r];
        s += __shfl_xor(s, 1, 64);
        s += __shfl_xor(s, 2, 64);
        s += __shfl_xor(s, 4, 64);
        s += __shfl_xor(s, 8, 64);
        linv[r] = 1.f / s;
    }

    #pragma unroll
    for (int t = 0; t < 6; ++t)
        #pragma unroll
        for (int r = 0; r < 4; ++r) {
            const int row = q0 + g * 4 + r;
            if (row < N_)
                Out[((size_t)(b * N_ + row)) * 768 + hh * 96 + t * 16 + c] =
                    f2bf(oacc[t][r] * linv[r]);
        }
}

// ---------------------------------------------------------------------------
extern "C" void kernel_launch(void* const* d_in, const int* in_sizes, int n_in,
                              void* d_out, int out_size, void* d_ws, size_t ws_size,
                              hipStream_t stream)
{
    const float* x     = (const float*)d_in[0];
    const float* Wqkv  = (const float*)d_in[1];
    const float* bqkv  = (const float*)d_in[2];
    const float* Wproj = (const float*)d_in[3];
    const float* bproj = (const float*)d_in[4];
    const float* cwq   = (const float*)d_in[5];
    const float* cwk   = (const float*)d_in[6];
    const float* cwv   = (const float*)d_in[7];
    const float* lnqg  = (const float*)d_in[8];
    const float* lnqb  = (const float*)d_in[9];
    const float* lnkg  = (const float*)d_in[10];
    const float* lnkb  = (const float*)d_in[11];
    const float* lnvg  = (const float*)d_in[12];
    const float* lnvb  = (const float*)d_in[13];

    u16* ws = (u16*)d_ws;
    u16* qkv_raw = ws;                       // 3 x [B][NH][N][D] bf16
    u16* q16 = qkv_raw + 3 * QKV1;           // [64][QPAD][96]
    u16* k16 = q16 + (size_t)64 * QPAD * 96; // [64][KPAD][96]
    u16* vt16 = k16 + (size_t)64 * KPAD * 96;// [64][96][KPAD] (transposed)
    u16* x16    = vt16 + (size_t)64 * KPAD * 96;  // [12552][768]
    u16* Wqkvt  = x16 + (size_t)M_ * 768;         // [2304][768]
    u16* Wprojt = Wqkvt + (size_t)2304 * 768;     // [768][768]
    u16* attn16 = qkv_raw;                   // alias: raw dead after pooling
    float* out = (float*)d_out;

    // 0) converts / transposes / VT pad zero
    cvt_f32_to_bf16<<<(M_ * 768 / 4 + 255) / 256, 256, 0, stream>>>(x, x16, M_ * 768 / 4);
    transpose_cvt<<<dim3(2304 / 32, 768 / 32), 256, 0, stream>>>(Wqkv, Wqkvt, 2304);
    transpose_cvt<<<dim3(768 / 32, 768 / 32), 256, 0, stream>>>(Wproj, Wprojt, 768);
    zero_pad_vt<<<(64 * 96 * (KPAD - NKV_) + 255) / 256, 256, 0, stream>>>(vt16);

    // 1) qkv GEMM (pipelined MFMA) with bf16 scatter into q/k/v
    gemm_bf16_kernel<2304, true><<<18 * 99, 256, 0, stream>>>(x16, Wqkvt, bqkv, qkv_raw);

    // 2) pool + LN (q normal; k normal; v transposed)
    pool_ln_q_kernel<<<dim3(29, 64), 256, 0, stream>>>(qkv_raw, cwq, lnqg, lnqb, q16);
    pool_ln_kv_kernel<<<dim3(15, 128), 256, 0, stream>>>(
        qkv_raw + QKV1, cwk, lnkg, lnkb, k16,
        qkv_raw + 2 * QKV1, cwv, lnvg, lnvb, vt16);

    // 3) MFMA attention -> bf16 [M_][768]
    attn_mfma_kernel<<<25 * 64, 256, 0, stream>>>(q16, k16, vt16, attn16);

    // 4) output projection (pipelined MFMA) -> fp32 d_out
    gemm_bf16_kernel<768, false><<<6 * 99, 256, 0, stream>>>(attn16, Wprojt, bproj, out);
}

// Round 7
// 300.004 us; speedup vs baseline: 19.2940x; 1.0095x over previous
//
#include <hip/hip_runtime.h>
#include <hip/hip_bf16.h>
#include <math.h>

#define B_   8
#define NH_  8
#define D_   96
#define C_   768
#define N_   1569          // 8*14*14 + 1
#define NKV_ 393           // 8*7*7 + 1
#define M_   (B_*N_)       // 12552
#define QKV1 ((size_t)B_*NH_*N_*D_)    // 9,639,936 elems per tensor
#define QPAD 1600          // padded q rows per slab (25 tiles of 64)
#define KPAD 416           // padded kv rows per slab (13 tiles of 32)
#define SCALE_ 0.10206207261596575f    // 96^-0.5

using short8v = __attribute__((ext_vector_type(8))) short;
using f32x4   = __attribute__((ext_vector_type(4))) float;
typedef unsigned short u16;

#define GLOAD_LDS16(g, l) __builtin_amdgcn_global_load_lds( \
    (const __attribute__((address_space(1))) void*)(g),     \
    (__attribute__((address_space(3))) void*)(l), 16, 0, 0)

static __device__ __forceinline__ u16 f2bf(float f) {
    __hip_bfloat16 b = __float2bfloat16(f);
    return *(u16*)&b;
}
static __device__ __forceinline__ float bf2f(u16 v) {
    return __bfloat162float(*(const __hip_bfloat16*)&v);
}

// bijective XCD swizzle (m204): consecutive swizzled ids land on one XCD
static __device__ __forceinline__ unsigned xcd_swizzle(unsigned orig, unsigned nwg) {
    const unsigned qq = nwg >> 3, rr = nwg & 7;
    const unsigned xcd = orig & 7, loc = orig >> 3;
    return (xcd < rr ? xcd * (qq + 1) : rr * (qq + 1) + (xcd - rr) * qq) + loc;
}

// ---------------------------------------------------------------------------
// fp32 -> bf16 flat convert (n4 float4 chunks)
// ---------------------------------------------------------------------------
__global__ __launch_bounds__(256)
void cvt_f32_to_bf16(const float* __restrict__ in, u16* __restrict__ out, int n4)
{
    const int i = blockIdx.x * 256 + threadIdx.x;
    if (i < n4) {
        const float4 v = ((const float4*)in)[i];
        ushort4 o;
        o.x = f2bf(v.x); o.y = f2bf(v.y); o.z = f2bf(v.z); o.w = f2bf(v.w);
        ((ushort4*)out)[i] = o;
    }
}

// ---------------------------------------------------------------------------
// W [768][ncols] fp32  ->  Wt [ncols][768] bf16   (32x32 LDS tiles)
// ---------------------------------------------------------------------------
__global__ __launch_bounds__(256)
void transpose_cvt(const float* __restrict__ W, u16* __restrict__ Wt, int ncols)
{
    __shared__ float tile[32][33];
    const int tx = threadIdx.x & 31, ty = threadIdx.x >> 5;   // 32 x 8
    const int n0 = blockIdx.x * 32, k0 = blockIdx.y * 32;
    #pragma unroll
    for (int i = 0; i < 4; ++i)
        tile[ty + i * 8][tx] = W[(size_t)(k0 + ty + i * 8) * ncols + n0 + tx];
    __syncthreads();
    #pragma unroll
    for (int i = 0; i < 4; ++i)
        Wt[(size_t)(n0 + ty + i * 8) * 768 + k0 + tx] = f2bf(tile[tx][ty + i * 8]);
}

// ---------------------------------------------------------------------------
// zero V^T pad columns (j in [NKV_, KPAD)) — required finite for PV MFMA
// ---------------------------------------------------------------------------
__global__ __launch_bounds__(256)
void zero_pad_vt(u16* __restrict__ vt)
{
    const int i = blockIdx.x * 256 + threadIdx.x;
    const int total = 64 * 96 * (KPAD - NKV_);
    if (i < total) {
        const int j = i % (KPAD - NKV_);
        const int rest = i / (KPAD - NKV_);     // slab*96 + d
        vt[(size_t)rest * KPAD + NKV_ + j] = 0;
    }
}

// ---------------------------------------------------------------------------
// bf16 MFMA GEMM, counted-vmcnt pipeline (T3+T4) + LDS XOR swizzle (T2).
// ---------------------------------------------------------------------------
template<int NC, bool SCATTER>
__global__ __launch_bounds__(256)
void gemm_bf16_kernel(const u16* __restrict__ A, const u16* __restrict__ Bt,
                      const float* __restrict__ bias, void* __restrict__ outp)
{
    constexpr int NXT = NC / 128;
    __shared__ alignas(16) u16 As[2][128 * 64];
    __shared__ alignas(16) u16 Bs[2][128 * 64];

    const int tid  = threadIdx.x;
    const int w    = tid >> 6, lane = tid & 63;
    const int c    = lane & 15, g = lane >> 4;
    const int wm   = w >> 1, wn = w & 1;
    const int lrow = lane >> 3, lcol = lane & 7;

    const unsigned wg = xcd_swizzle(blockIdx.x, gridDim.x);
    const int m0 = (int)(wg / NXT) * 128;
    const int n0 = (int)(wg % NXT) * 128;

    f32x4 acc[4][4];
    #pragma unroll
    for (int i = 0; i < 4; ++i)
        #pragma unroll
        for (int j = 0; j < 4; ++j) acc[i][j] = (f32x4){0.f, 0.f, 0.f, 0.f};

#define STAGE(BUF, K0) do {                                                      \
    _Pragma("unroll")                                                            \
    for (int t = 0; t < 4; ++t) {                                                \
        const int r = t * 32 + w * 8;                                            \
        const int row = r + lrow;                                                \
        const int scol = (lcol ^ (row & 7)) * 8;                                 \
        int m = m0 + row; if (m >= M_) m = M_ - 1;                               \
        GLOAD_LDS16(&A[(size_t)m * 768 + (K0) + scol], &As[BUF][r * 64]);        \
        GLOAD_LDS16(&Bt[(size_t)(n0 + row) * 768 + (K0) + scol],                 \
                    &Bs[BUF][r * 64]);                                           \
    } } while (0)

    const int xora = (g ^ (c & 7)) * 8;          // kk=0: logical col16 = g
    const int xorb = ((4 + g) ^ (c & 7)) * 8;    // kk=1: logical col16 = 4+g

#define KSTEP(BUF, LAST, PREF, KNEXT) do {                                       \
    if (LAST) asm volatile("s_waitcnt vmcnt(0)" ::: "memory");                   \
    else      asm volatile("s_waitcnt vmcnt(8)" ::: "memory");                   \
    __builtin_amdgcn_s_barrier();                                                \
    short8v a0[4], a1[4], b0[4], b1[4];                                          \
    _Pragma("unroll")                                                            \
    for (int i = 0; i < 4; ++i) {                                                \
        const int ra = (wm * 64 + i * 16 + c) * 64;                              \
        const int rb = (wn * 64 + i * 16 + c) * 64;                              \
        a0[i] = *(const short8v*)&As[BUF][ra + xora];                            \
        a1[i] = *(const short8v*)&As[BUF][ra + xorb];                            \
        b0[i] = *(const short8v*)&Bs[BUF][rb + xora];                            \
        b1[i] = *(const short8v*)&Bs[BUF][rb + xorb];                            \
    }                                                                            \
    asm volatile("s_waitcnt lgkmcnt(0)" ::: "memory");                           \
    __builtin_amdgcn_sched_barrier(0);                                           \
    __builtin_amdgcn_s_barrier();                                                \
    if (PREF) STAGE(BUF, KNEXT);                                                 \
    _Pragma("unroll")                                                            \
    for (int i = 0; i < 4; ++i)                                                  \
        _Pragma("unroll")                                                        \
        for (int j = 0; j < 4; ++j)                                              \
            acc[i][j] = __builtin_amdgcn_mfma_f32_16x16x32_bf16(                 \
                a0[i], b0[j], acc[i][j], 0, 0, 0);                               \
    _Pragma("unroll")                                                            \
    for (int i = 0; i < 4; ++i)                                                  \
        _Pragma("unroll")                                                        \
        for (int j = 0; j < 4; ++j)                                              \
            acc[i][j] = __builtin_amdgcn_mfma_f32_16x16x32_bf16(                 \
                a1[i], b1[j], acc[i][j], 0, 0, 0);                               \
    } while (0)

    STAGE(0, 0);
    STAGE(1, 64);
    #pragma unroll
    for (int tt = 0; tt < 5; ++tt) {
        KSTEP(0, false, true, (2 * tt + 2) * 64);
        KSTEP(1, false, true, (2 * tt + 3) * 64);
    }
    KSTEP(0, false, false, 0);
    KSTEP(1, true,  false, 0);
#undef STAGE
#undef KSTEP

    #pragma unroll
    for (int i = 0; i < 4; ++i) {
        const int mrow = m0 + wm * 64 + i * 16 + g * 4;
        #pragma unroll
        for (int j = 0; j < 4; ++j) {
            const int ncol = n0 + wn * 64 + j * 16 + c;
            const float bv = bias[ncol];
            if constexpr (SCATTER) {
                u16* out = (u16*)outp;
                const int s   = ncol / C_;          // 0=q,1=k,2=v
                const int rem = ncol - s * C_;
                const int hh  = rem / D_;
                const int dd  = rem - hh * D_;
                #pragma unroll
                for (int r = 0; r < 4; ++r) {
                    const int m = mrow + r;
                    if (m < M_) {
                        const int bb2 = m / N_;
                        const int n = m - bb2 * N_;
                        out[(size_t)s * QKV1 +
                            ((size_t)(bb2 * NH_ + hh) * N_ + n) * D_ + dd] = f2bf(acc[i][j][r] + bv);
                    }
                }
            } else {
                float* out = (float*)outp;
                #pragma unroll
                for (int r = 0; r < 4; ++r) {
                    const int m = mrow + r;
                    if (m < M_) out[(size_t)m * NC + ncol] = acc[i][j][r] + bv;
                }
            }
        }
    }
}

// ---------------------------------------------------------------------------
// Block-level pool+LN: one block per (bh, to). Stage 3 input t-planes
// (3*196 tokens * 96ch bf16 = 112.9KB) into LDS via global_load_lds, then
// compute all (OH*OW) outputs of this to from LDS. Lane<48 owns channel
// pair (2l, 2l+1). MODE: 0=q([tok][96], scaled), 1=k([tok][96]), 2=v^T.
// ---------------------------------------------------------------------------
#define PLANE_B 37632              // 196*192 bytes per t-plane
#define POOL_LDS_B (114688 + 96*27*4)
template<int STRIDE, int OH, int OW, int MODE>
__global__ __launch_bounds__(256, 1)
void pool_ln_block_kernel(const u16* __restrict__ in, const float* __restrict__ cw,
                          const float* __restrict__ g, const float* __restrict__ bta,
                          u16* __restrict__ out, int tokstride, float oscale)
{
    extern __shared__ u16 smem[];              // [3][196][96] (+pad to 114688B)
    float* wsm2 = (float*)(smem + 57344);      // [27][96] transposed weights

    const int tid = threadIdx.x;
    const int wv = tid >> 6, lane = tid & 63;

    for (int i = tid; i < 96 * 27; i += 256) {
        const int tap = i / 96, ch = i - tap * 96;
        wsm2[i] = cw[ch * 27 + tap];
    }

    const unsigned wg = xcd_swizzle(blockIdx.x, gridDim.x);
    const int bh = (int)(wg >> 3);
    const int to = (int)(wg & 7);
    const size_t inbase = (size_t)bh * N_ * 96;

    // stage planes p=0..2 holding t = clamp(to-1+p, 0, 7)
    #pragma unroll
    for (int it = 0; it < 28; ++it) {
        const int byte = (it * 256 + tid) * 16;
        int plane = byte / PLANE_B; if (plane > 2) plane = 2;
        const int rem = byte - plane * PLANE_B;
        const int tok = rem / 192;
        const int chb = rem - tok * 192;
        int t = to - 1 + plane; if (t < 0) t = 0; if (t > 7) t = 7;
        const u16* gsrc = in + inbase + (size_t)(1 + t * 196 + tok) * 96 + (chb >> 1);
        GLOAD_LDS16(gsrc, smem + (size_t)(it * 256 + wv * 64) * 8);
    }
    __syncthreads();

    const int l = lane < 48 ? lane : 47;
    const bool act = lane < 48;

    float wg0[27], wg1[27];
    #pragma unroll
    for (int tap = 0; tap < 27; ++tap) {
        const float2 wp = *(const float2*)&wsm2[tap * 96 + 2 * l];
        wg0[tap] = wp.x; wg1[tap] = wp.y;
    }
    const float gam0 = g[2 * l],     bet0 = bta[2 * l];
    const float gam1 = g[2 * l + 1], bet1 = bta[2 * l + 1];

    for (int ho = wv; ho < OH; ho += 4) {
        float a0[OW], a1[OW];
        #pragma unroll
        for (int wo = 0; wo < OW; ++wo) { a0[wo] = 0.f; a1[wo] = 0.f; }

        #pragma unroll
        for (int dt = 0; dt < 3; ++dt) {
            const int t = to - 1 + dt;
            if (t < 0 || t > 7) continue;
            #pragma unroll
            for (int dh = 0; dh < 3; ++dh) {
                const int h = ho * STRIDE - 1 + dh;
                if (h < 0 || h >= 14) continue;
                float xl[14], xh[14];
                #pragma unroll
                for (int iw = 0; iw < 14; ++iw) {
                    const unsigned u = *(const unsigned*)
                        &smem[(dt * 196 + h * 14 + iw) * 96 + 2 * l];
                    xl[iw] = __uint_as_float(u << 16);
                    xh[iw] = __uint_as_float(u & 0xffff0000u);
                }
                const int tapb = dt * 9 + dh * 3;
                #pragma unroll
                for (int wo = 0; wo < OW; ++wo)
                    #pragma unroll
                    for (int dw = 0; dw < 3; ++dw) {
                        const int iw = wo * STRIDE - 1 + dw;
                        if (iw < 0 || iw >= 14) continue;   // compile-time
                        a0[wo] += wg0[tapb + dw] * xl[iw];
                        a1[wo] += wg1[tapb + dw] * xh[iw];
                    }
            }
        }

        #pragma unroll
        for (int wo = 0; wo < OW; ++wo) {
            const float va = act ? a0[wo] : 0.f, vb = act ? a1[wo] : 0.f;
            float s = va + vb;
            #pragma unroll
            for (int off = 32; off; off >>= 1) s += __shfl_xor(s, off, 64);
            float sq = va * va + vb * vb;
            #pragma unroll
            for (int off = 32; off; off >>= 1) sq += __shfl_xor(sq, off, 64);
            const float mu = s * (1.f / 96.f);
            const float rstd = rsqrtf(sq * (1.f / 96.f) - mu * mu + 1e-5f);
            const float y0 = ((va - mu) * rstd * gam0 + bet0) * oscale;
            const float y1 = ((vb - mu) * rstd * gam1 + bet1) * oscale;
            const int tok = 1 + (to * OH + ho) * OW + wo;
            if (act) {
                if constexpr (MODE == 2) {
                    out[((size_t)bh * 96 + 2 * l) * KPAD + tok] = f2bf(y0);
                    out[((size_t)bh * 96 + 2 * l + 1) * KPAD + tok] = f2bf(y1);
                } else {
                    const unsigned pk = (unsigned)f2bf(y0) | ((unsigned)f2bf(y1) << 16);
                    *(unsigned*)&out[((size_t)bh * tokstride + tok) * 96 + 2 * l] = pk;
                }
            }
        }
    }

    if (to == 0 && wv == 3) {        // cls token: LN only
        const unsigned u = *(const unsigned*)&in[inbase + 2 * l];
        const float va = act ? __uint_as_float(u << 16) : 0.f;
        const float vb = act ? __uint_as_float(u & 0xffff0000u) : 0.f;
        float s = va + vb;
        #pragma unroll
        for (int off = 32; off; off >>= 1) s += __shfl_xor(s, off, 64);
        float sq = va * va + vb * vb;
        #pragma unroll
        for (int off = 32; off; off >>= 1) sq += __shfl_xor(sq, off, 64);
        const float mu = s * (1.f / 96.f);
        const float rstd = rsqrtf(sq * (1.f / 96.f) - mu * mu + 1e-5f);
        const float y0 = ((va - mu) * rstd * gam0 + bet0) * oscale;
        const float y1 = ((vb - mu) * rstd * gam1 + bet1) * oscale;
        if (act) {
            if constexpr (MODE == 2) {
                out[((size_t)bh * 96 + 2 * l) * KPAD] = f2bf(y0);
                out[((size_t)bh * 96 + 2 * l + 1) * KPAD] = f2bf(y1);
            } else {
                const unsigned pk = (unsigned)f2bf(y0) | ((unsigned)f2bf(y1) << 16);
                *(unsigned*)&out[(size_t)bh * tokstride * 96 + 2 * l] = pk;
            }
        }
    }
}

// ---------------------------------------------------------------------------
// MFMA attention -> bf16 [M_][768]. Q pre-scaled. V is transposed [96][KPAD].
// ---------------------------------------------------------------------------
__global__ __launch_bounds__(256)
void attn_mfma_kernel(const u16* __restrict__ Q, const u16* __restrict__ K,
                      const u16* __restrict__ VT, u16* __restrict__ Out)
{
    __shared__ alignas(16) u16 plds[4][512];   // per-wave 16x32 bf16 P tile
    const int tid  = threadIdx.x;
    const int w    = tid >> 6, lane = tid & 63;
    const int c    = lane & 15, g = lane >> 4;

    const unsigned wg = xcd_swizzle(blockIdx.x, gridDim.x);
    const int bh = (int)(wg / 25);
    const int b  = bh >> 3, hh = bh & 7;
    const int q0 = (int)(wg % 25) * 64 + w * 16;
    const int qrow = q0 + c;

    const size_t qbase = (size_t)bh * QPAD * 96;
    const size_t kbase = (size_t)bh * KPAD * 96;

    short8v qa[3];
    #pragma unroll
    for (int kf = 0; kf < 3; ++kf)
        qa[kf] = *(const short8v*)&Q[qbase + (size_t)qrow * 96 + kf * 32 + g * 8];

    f32x4 oacc[6];
    #pragma unroll
    for (int t = 0; t < 6; ++t) oacc[t] = (f32x4){0.f, 0.f, 0.f, 0.f};
    float lsum[4] = {0.f, 0.f, 0.f, 0.f};

    for (int pr = 0; pr < 13; ++pr) {
        #pragma unroll
        for (int h = 0; h < 2; ++h) {
            const int jcol = pr * 32 + h * 16 + c;
            const u16* kp = &K[kbase + (size_t)jcol * 96 + g * 8];
            short8v kb0 = *(const short8v*)&kp[0];
            short8v kb1 = *(const short8v*)&kp[32];
            short8v kb2 = *(const short8v*)&kp[64];
            f32x4 sacc = (f32x4){0.f, 0.f, 0.f, 0.f};
            sacc = __builtin_amdgcn_mfma_f32_16x16x32_bf16(qa[0], kb0, sacc, 0, 0, 0);
            sacc = __builtin_amdgcn_mfma_f32_16x16x32_bf16(qa[1], kb1, sacc, 0, 0, 0);
            sacc = __builtin_amdgcn_mfma_f32_16x16x32_bf16(qa[2], kb2, sacc, 0, 0, 0);
            #pragma unroll
            for (int r = 0; r < 4; ++r) {
                float s = sacc[r];
                if (jcol >= NKV_) s = -1e30f;
                const float p = __expf(s);
                lsum[r] += p;
                const int q    = g * 4 + r;
                const int j    = h * 16 + c;
                const int dstL = q | ((j >> 3) << 4);
                plds[w][dstL * 8 + (j & 7)] = f2bf(p);
            }
        }
        asm volatile("s_waitcnt lgkmcnt(0)" ::: "memory");
        const short8v pa = *(const short8v*)&plds[w][lane * 8];

        #pragma unroll
        for (int t = 0; t < 6; ++t) {
            const int d0 = t * 16;
            const short8v vb = *(const short8v*)
                &VT[kbase + (size_t)(d0 + c) * KPAD + pr * 32 + g * 8];
            oacc[t] = __builtin_amdgcn_mfma_f32_16x16x32_bf16(pa, vb, oacc[t], 0, 0, 0);
        }
    }

    float linv[4];
    #pragma unroll
    for (int r = 0; r < 4; ++r) {
        float s = lsum[r];
        s += __shfl_xor(s, 1, 64);
        s += __shfl_xor(s, 2, 64);
        s += __shfl_xor(s, 4, 64);
        s += __shfl_xor(s, 8, 64);
        linv[r] = 1.f / s;
    }

    #pragma unroll
    for (int t = 0; t < 6; ++t)
        #pragma unroll
        for (int r = 0; r < 4; ++r) {
            const int row = q0 + g * 4 + r;
            if (row < N_)
                Out[((size_t)(b * N_ + row)) * 768 + hh * 96 + t * 16 + c] =
                    f2bf(oacc[t][r] * linv[r]);
        }
}

// ---------------------------------------------------------------------------
extern "C" void kernel_launch(void* const* d_in, const int* in_sizes, int n_in,
                              void* d_out, int out_size, void* d_ws, size_t ws_size,
                              hipStream_t stream)
{
    const float* x     = (const float*)d_in[0];
    const float* Wqkv  = (const float*)d_in[1];
    const float* bqkv  = (const float*)d_in[2];
    const float* Wproj = (const float*)d_in[3];
    const float* bproj = (const float*)d_in[4];
    const float* cwq   = (const float*)d_in[5];
    const float* cwk   = (const float*)d_in[6];
    const float* cwv   = (const float*)d_in[7];
    const float* lnqg  = (const float*)d_in[8];
    const float* lnqb  = (const float*)d_in[9];
    const float* lnkg  = (const float*)d_in[10];
    const float* lnkb  = (const float*)d_in[11];
    const float* lnvg  = (const float*)d_in[12];
    const float* lnvb  = (const float*)d_in[13];

    u16* ws = (u16*)d_ws;
    u16* qkv_raw = ws;                       // 3 x [B][NH][N][D] bf16
    u16* q16 = qkv_raw + 3 * QKV1;           // [64][QPAD][96]
    u16* k16 = q16 + (size_t)64 * QPAD * 96; // [64][KPAD][96]
    u16* vt16 = k16 + (size_t)64 * KPAD * 96;// [64][96][KPAD] (transposed)
    u16* x16    = vt16 + (size_t)64 * KPAD * 96;  // [12552][768]
    u16* Wqkvt  = x16 + (size_t)M_ * 768;         // [2304][768]
    u16* Wprojt = Wqkvt + (size_t)2304 * 768;     // [768][768]
    u16* attn16 = qkv_raw;                   // alias: raw dead after pooling
    float* out = (float*)d_out;

    // 0) converts / transposes / VT pad zero
    cvt_f32_to_bf16<<<(M_ * 768 / 4 + 255) / 256, 256, 0, stream>>>(x, x16, M_ * 768 / 4);
    transpose_cvt<<<dim3(2304 / 32, 768 / 32), 256, 0, stream>>>(Wqkv, Wqkvt, 2304);
    transpose_cvt<<<dim3(768 / 32, 768 / 32), 256, 0, stream>>>(Wproj, Wprojt, 768);
    zero_pad_vt<<<(64 * 96 * (KPAD - NKV_) + 255) / 256, 256, 0, stream>>>(vt16);

    // 1) qkv GEMM (pipelined MFMA) with bf16 scatter into q/k/v
    gemm_bf16_kernel<2304, true><<<18 * 99, 256, 0, stream>>>(x16, Wqkvt, bqkv, qkv_raw);

    // 2) block-level pool + LN (one block per (bh, to))
    pool_ln_block_kernel<1, 14, 14, 0><<<512, 256, POOL_LDS_B, stream>>>(
        qkv_raw, cwq, lnqg, lnqb, q16, QPAD, SCALE_);
    pool_ln_block_kernel<2, 7, 7, 1><<<512, 256, POOL_LDS_B, stream>>>(
        qkv_raw + QKV1, cwk, lnkg, lnkb, k16, KPAD, 1.f);
    pool_ln_block_kernel<2, 7, 7, 2><<<512, 256, POOL_LDS_B, stream>>>(
        qkv_raw + 2 * QKV1, cwv, lnvg, lnvb, vt16, KPAD, 1.f);

    // 3) MFMA attention -> bf16 [M_][768]
    attn_mfma_kernel<<<25 * 64, 256, 0, stream>>>(q16, k16, vt16, attn16);

    // 4) output projection (pipelined MFMA) -> fp32 d_out
    gemm_bf16_kernel<768, false><<<6 * 99, 256, 0, stream>>>(attn16, Wprojt, bproj, out);
}

// Round 8
// 274.093 us; speedup vs baseline: 21.1180x; 1.0945x over previous
//
#include <hip/hip_runtime.h>
#include <hip/hip_bf16.h>
#include <math.h>

#define B_   8
#define NH_  8
#define D_   96
#define C_   768
#define N_   1569          // 8*14*14 + 1
#define NKV_ 393           // 8*7*7 + 1
#define M_   (B_*N_)       // 12552
#define QKV1 ((size_t)B_*NH_*N_*D_)    // 9,639,936 elems per tensor
#define QPAD 1664          // padded q rows per slab (13 tiles of 128)
#define KPAD 416           // padded kv rows per slab (13 tiles of 32)
#define SCALE_ 0.10206207261596575f    // 96^-0.5

using short8v = __attribute__((ext_vector_type(8))) short;
using f32x4   = __attribute__((ext_vector_type(4))) float;
typedef unsigned short u16;

#define GLOAD_LDS16(g, l) __builtin_amdgcn_global_load_lds( \
    (const __attribute__((address_space(1))) void*)(g),     \
    (__attribute__((address_space(3))) void*)(l), 16, 0, 0)

static __device__ __forceinline__ u16 f2bf(float f) {
    __hip_bfloat16 b = __float2bfloat16(f);
    return *(u16*)&b;
}
static __device__ __forceinline__ float bf2f(u16 v) {
    return __bfloat162float(*(const __hip_bfloat16*)&v);
}

// bijective XCD swizzle (m204): consecutive swizzled ids land on one XCD
static __device__ __forceinline__ unsigned xcd_swizzle(unsigned orig, unsigned nwg) {
    const unsigned qq = nwg >> 3, rr = nwg & 7;
    const unsigned xcd = orig & 7, loc = orig >> 3;
    return (xcd < rr ? xcd * (qq + 1) : rr * (qq + 1) + (xcd - rr) * qq) + loc;
}

// ---------------------------------------------------------------------------
// fp32 -> bf16 flat convert (n4 float4 chunks)
// ---------------------------------------------------------------------------
__global__ __launch_bounds__(256)
void cvt_f32_to_bf16(const float* __restrict__ in, u16* __restrict__ out, int n4)
{
    const int i = blockIdx.x * 256 + threadIdx.x;
    if (i < n4) {
        const float4 v = ((const float4*)in)[i];
        ushort4 o;
        o.x = f2bf(v.x); o.y = f2bf(v.y); o.z = f2bf(v.z); o.w = f2bf(v.w);
        ((ushort4*)out)[i] = o;
    }
}

// ---------------------------------------------------------------------------
// W [768][ncols] fp32  ->  Wt [ncols][768] bf16   (32x32 LDS tiles)
// ---------------------------------------------------------------------------
__global__ __launch_bounds__(256)
void transpose_cvt(const float* __restrict__ W, u16* __restrict__ Wt, int ncols)
{
    __shared__ float tile[32][33];
    const int tx = threadIdx.x & 31, ty = threadIdx.x >> 5;   // 32 x 8
    const int n0 = blockIdx.x * 32, k0 = blockIdx.y * 32;
    #pragma unroll
    for (int i = 0; i < 4; ++i)
        tile[ty + i * 8][tx] = W[(size_t)(k0 + ty + i * 8) * ncols + n0 + tx];
    __syncthreads();
    #pragma unroll
    for (int i = 0; i < 4; ++i)
        Wt[(size_t)(n0 + ty + i * 8) * 768 + k0 + tx] = f2bf(tile[tx][ty + i * 8]);
}

// ---------------------------------------------------------------------------
// zero V^T pad columns (j in [NKV_, KPAD)) — required finite for PV MFMA
// ---------------------------------------------------------------------------
__global__ __launch_bounds__(256)
void zero_pad_vt(u16* __restrict__ vt)
{
    const int i = blockIdx.x * 256 + threadIdx.x;
    const int total = 64 * 96 * (KPAD - NKV_);
    if (i < total) {
        const int j = i % (KPAD - NKV_);
        const int rest = i / (KPAD - NKV_);     // slab*96 + d
        vt[(size_t)rest * KPAD + NKV_ + j] = 0;
    }
}

// ---------------------------------------------------------------------------
// bf16 MFMA GEMM, counted-vmcnt pipeline (T3+T4) + LDS XOR swizzle (T2).
// ---------------------------------------------------------------------------
template<int NC, bool SCATTER>
__global__ __launch_bounds__(256)
void gemm_bf16_kernel(const u16* __restrict__ A, const u16* __restrict__ Bt,
                      const float* __restrict__ bias, void* __restrict__ outp)
{
    constexpr int NXT = NC / 128;
    __shared__ alignas(16) u16 As[2][128 * 64];
    __shared__ alignas(16) u16 Bs[2][128 * 64];

    const int tid  = threadIdx.x;
    const int w    = tid >> 6, lane = tid & 63;
    const int c    = lane & 15, g = lane >> 4;
    const int wm   = w >> 1, wn = w & 1;
    const int lrow = lane >> 3, lcol = lane & 7;

    const unsigned wg = xcd_swizzle(blockIdx.x, gridDim.x);
    const int m0 = (int)(wg / NXT) * 128;
    const int n0 = (int)(wg % NXT) * 128;

    f32x4 acc[4][4];
    #pragma unroll
    for (int i = 0; i < 4; ++i)
        #pragma unroll
        for (int j = 0; j < 4; ++j) acc[i][j] = (f32x4){0.f, 0.f, 0.f, 0.f};

#define STAGE(BUF, K0) do {                                                      \
    _Pragma("unroll")                                                            \
    for (int t = 0; t < 4; ++t) {                                                \
        const int r = t * 32 + w * 8;                                            \
        const int row = r + lrow;                                                \
        const int scol = (lcol ^ (row & 7)) * 8;                                 \
        int m = m0 + row; if (m >= M_) m = M_ - 1;                               \
        GLOAD_LDS16(&A[(size_t)m * 768 + (K0) + scol], &As[BUF][r * 64]);        \
        GLOAD_LDS16(&Bt[(size_t)(n0 + row) * 768 + (K0) + scol],                 \
                    &Bs[BUF][r * 64]);                                           \
    } } while (0)

    const int xora = (g ^ (c & 7)) * 8;          // kk=0: logical col16 = g
    const int xorb = ((4 + g) ^ (c & 7)) * 8;    // kk=1: logical col16 = 4+g

#define KSTEP(BUF, LAST, PREF, KNEXT) do {                                       \
    if (LAST) asm volatile("s_waitcnt vmcnt(0)" ::: "memory");                   \
    else      asm volatile("s_waitcnt vmcnt(8)" ::: "memory");                   \
    __builtin_amdgcn_s_barrier();                                                \
    short8v a0[4], a1[4], b0[4], b1[4];                                          \
    _Pragma("unroll")                                                            \
    for (int i = 0; i < 4; ++i) {                                                \
        const int ra = (wm * 64 + i * 16 + c) * 64;                              \
        const int rb = (wn * 64 + i * 16 + c) * 64;                              \
        a0[i] = *(const short8v*)&As[BUF][ra + xora];                            \
        a1[i] = *(const short8v*)&As[BUF][ra + xorb];                            \
        b0[i] = *(const short8v*)&Bs[BUF][rb + xora];                            \
        b1[i] = *(const short8v*)&Bs[BUF][rb + xorb];                            \
    }                                                                            \
    asm volatile("s_waitcnt lgkmcnt(0)" ::: "memory");                           \
    __builtin_amdgcn_sched_barrier(0);                                           \
    __builtin_amdgcn_s_barrier();                                                \
    if (PREF) STAGE(BUF, KNEXT);                                                 \
    _Pragma("unroll")                                                            \
    for (int i = 0; i < 4; ++i)                                                  \
        _Pragma("unroll")                                                        \
        for (int j = 0; j < 4; ++j)                                              \
            acc[i][j] = __builtin_amdgcn_mfma_f32_16x16x32_bf16(                 \
                a0[i], b0[j], acc[i][j], 0, 0, 0);                               \
    _Pragma("unroll")                                                            \
    for (int i = 0; i < 4; ++i)                                                  \
        _Pragma("unroll")                                                        \
        for (int j = 0; j < 4; ++j)                                              \
            acc[i][j] = __builtin_amdgcn_mfma_f32_16x16x32_bf16(                 \
                a1[i], b1[j], acc[i][j], 0, 0, 0);                               \
    } while (0)

    STAGE(0, 0);
    STAGE(1, 64);
    #pragma unroll
    for (int tt = 0; tt < 5; ++tt) {
        KSTEP(0, false, true, (2 * tt + 2) * 64);
        KSTEP(1, false, true, (2 * tt + 3) * 64);
    }
    KSTEP(0, false, false, 0);
    KSTEP(1, true,  false, 0);
#undef STAGE
#undef KSTEP

    #pragma unroll
    for (int i = 0; i < 4; ++i) {
        const int mrow = m0 + wm * 64 + i * 16 + g * 4;
        #pragma unroll
        for (int j = 0; j < 4; ++j) {
            const int ncol = n0 + wn * 64 + j * 16 + c;
            const float bv = bias[ncol];
            if constexpr (SCATTER) {
                u16* out = (u16*)outp;
                const int s   = ncol / C_;          // 0=q,1=k,2=v
                const int rem = ncol - s * C_;
                const int hh  = rem / D_;
                const int dd  = rem - hh * D_;
                #pragma unroll
                for (int r = 0; r < 4; ++r) {
                    const int m = mrow + r;
                    if (m < M_) {
                        const int bb2 = m / N_;
                        const int n = m - bb2 * N_;
                        out[(size_t)s * QKV1 +
                            ((size_t)(bb2 * NH_ + hh) * N_ + n) * D_ + dd] = f2bf(acc[i][j][r] + bv);
                    }
                }
            } else {
                float* out = (float*)outp;
                #pragma unroll
                for (int r = 0; r < 4; ++r) {
                    const int m = mrow + r;
                    if (m < M_) out[(size_t)m * NC + ncol] = acc[i][j][r] + bv;
                }
            }
        }
    }
}

// ---------------------------------------------------------------------------
// Block-level pool+LN: one block per (bh, to). Stage 3 input t-planes into
// LDS via global_load_lds, compute all outputs. MODE: 0=q, 1=k, 2=v^T.
// ---------------------------------------------------------------------------
#define PLANE_B 37632              // 196*192 bytes per t-plane
#define POOL_LDS_B (114688 + 96*27*4)
template<int STRIDE, int OH, int OW, int MODE>
__global__ __launch_bounds__(256, 1)
void pool_ln_block_kernel(const u16* __restrict__ in, const float* __restrict__ cw,
                          const float* __restrict__ g, const float* __restrict__ bta,
                          u16* __restrict__ out, int tokstride, float oscale)
{
    extern __shared__ u16 smem[];              // [3][196][96] (+pad to 114688B)
    float* wsm2 = (float*)(smem + 57344);      // [27][96] transposed weights

    const int tid = threadIdx.x;
    const int wv = tid >> 6, lane = tid & 63;

    for (int i = tid; i < 96 * 27; i += 256) {
        const int tap = i / 96, ch = i - tap * 96;
        wsm2[i] = cw[ch * 27 + tap];
    }

    const unsigned wg = xcd_swizzle(blockIdx.x, gridDim.x);
    const int bh = (int)(wg >> 3);
    const int to = (int)(wg & 7);
    const size_t inbase = (size_t)bh * N_ * 96;

    #pragma unroll
    for (int it = 0; it < 28; ++it) {
        const int byte = (it * 256 + tid) * 16;
        int plane = byte / PLANE_B; if (plane > 2) plane = 2;
        const int rem = byte - plane * PLANE_B;
        const int tok = rem / 192;
        const int chb = rem - tok * 192;
        int t = to - 1 + plane; if (t < 0) t = 0; if (t > 7) t = 7;
        const u16* gsrc = in + inbase + (size_t)(1 + t * 196 + tok) * 96 + (chb >> 1);
        GLOAD_LDS16(gsrc, smem + (size_t)(it * 256 + wv * 64) * 8);
    }
    __syncthreads();

    const int l = lane < 48 ? lane : 47;
    const bool act = lane < 48;

    float wg0[27], wg1[27];
    #pragma unroll
    for (int tap = 0; tap < 27; ++tap) {
        const float2 wp = *(const float2*)&wsm2[tap * 96 + 2 * l];
        wg0[tap] = wp.x; wg1[tap] = wp.y;
    }
    const float gam0 = g[2 * l],     bet0 = bta[2 * l];
    const float gam1 = g[2 * l + 1], bet1 = bta[2 * l + 1];

    for (int ho = wv; ho < OH; ho += 4) {
        float a0[OW], a1[OW];
        #pragma unroll
        for (int wo = 0; wo < OW; ++wo) { a0[wo] = 0.f; a1[wo] = 0.f; }

        #pragma unroll
        for (int dt = 0; dt < 3; ++dt) {
            const int t = to - 1 + dt;
            if (t < 0 || t > 7) continue;
            #pragma unroll
            for (int dh = 0; dh < 3; ++dh) {
                const int h = ho * STRIDE - 1 + dh;
                if (h < 0 || h >= 14) continue;
                float xl[14], xh[14];
                #pragma unroll
                for (int iw = 0; iw < 14; ++iw) {
                    const unsigned u = *(const unsigned*)
                        &smem[(dt * 196 + h * 14 + iw) * 96 + 2 * l];
                    xl[iw] = __uint_as_float(u << 16);
                    xh[iw] = __uint_as_float(u & 0xffff0000u);
                }
                const int tapb = dt * 9 + dh * 3;
                #pragma unroll
                for (int wo = 0; wo < OW; ++wo)
                    #pragma unroll
                    for (int dw = 0; dw < 3; ++dw) {
                        const int iw = wo * STRIDE - 1 + dw;
                        if (iw < 0 || iw >= 14) continue;   // compile-time
                        a0[wo] += wg0[tapb + dw] * xl[iw];
                        a1[wo] += wg1[tapb + dw] * xh[iw];
                    }
            }
        }

        #pragma unroll
        for (int wo = 0; wo < OW; ++wo) {
            const float va = act ? a0[wo] : 0.f, vb = act ? a1[wo] : 0.f;
            float s = va + vb;
            #pragma unroll
            for (int off = 32; off; off >>= 1) s += __shfl_xor(s, off, 64);
            float sq = va * va + vb * vb;
            #pragma unroll
            for (int off = 32; off; off >>= 1) sq += __shfl_xor(sq, off, 64);
            const float mu = s * (1.f / 96.f);
            const float rstd = rsqrtf(sq * (1.f / 96.f) - mu * mu + 1e-5f);
            const float y0 = ((va - mu) * rstd * gam0 + bet0) * oscale;
            const float y1 = ((vb - mu) * rstd * gam1 + bet1) * oscale;
            const int tok = 1 + (to * OH + ho) * OW + wo;
            if (act) {
                if constexpr (MODE == 2) {
                    out[((size_t)bh * 96 + 2 * l) * KPAD + tok] = f2bf(y0);
                    out[((size_t)bh * 96 + 2 * l + 1) * KPAD + tok] = f2bf(y1);
                } else {
                    const unsigned pk = (unsigned)f2bf(y0) | ((unsigned)f2bf(y1) << 16);
                    *(unsigned*)&out[((size_t)bh * tokstride + tok) * 96 + 2 * l] = pk;
                }
            }
        }
    }

    if (to == 0 && wv == 3) {        // cls token: LN only
        const unsigned u = *(const unsigned*)&in[inbase + 2 * l];
        const float va = act ? __uint_as_float(u << 16) : 0.f;
        const float vb = act ? __uint_as_float(u & 0xffff0000u) : 0.f;
        float s = va + vb;
        #pragma unroll
        for (int off = 32; off; off >>= 1) s += __shfl_xor(s, off, 64);
        float sq = va * va + vb * vb;
        #pragma unroll
        for (int off = 32; off; off >>= 1) sq += __shfl_xor(sq, off, 64);
        const float mu = s * (1.f / 96.f);
        const float rstd = rsqrtf(sq * (1.f / 96.f) - mu * mu + 1e-5f);
        const float y0 = ((va - mu) * rstd * gam0 + bet0) * oscale;
        const float y1 = ((vb - mu) * rstd * gam1 + bet1) * oscale;
        if (act) {
            if constexpr (MODE == 2) {
                out[((size_t)bh * 96 + 2 * l) * KPAD] = f2bf(y0);
                out[((size_t)bh * 96 + 2 * l + 1) * KPAD] = f2bf(y1);
            } else {
                const unsigned pk = (unsigned)f2bf(y0) | ((unsigned)f2bf(y1) << 16);
                *(unsigned*)&out[(size_t)bh * tokstride * 96 + 2 * l] = pk;
            }
        }
    }
}

// ---------------------------------------------------------------------------
// MFMA attention v2 -> bf16 [M_][768]. 32 q-rows/wave (2 subtiles), K reg
// double-buffer prefetch, VT loads hoisted before softmax. Q pre-scaled.
// Grid 13*64, 4 waves/block (128 q rows).
// ---------------------------------------------------------------------------
__global__ __launch_bounds__(256)
void attn_mfma_kernel(const u16* __restrict__ Q, const u16* __restrict__ K,
                      const u16* __restrict__ VT, u16* __restrict__ Out)
{
    __shared__ alignas(16) u16 plds[4][2][512];   // per-wave, per-subtile P tile
    const int tid  = threadIdx.x;
    const int w    = tid >> 6, lane = tid & 63;
    const int c    = lane & 15, g = lane >> 4;

    const unsigned wg = xcd_swizzle(blockIdx.x, gridDim.x);
    const int bh = (int)(wg / 13);
    const int b  = bh >> 3, hh = bh & 7;
    const int q0 = (int)(wg % 13) * 128 + w * 32;

    const size_t qbase = (size_t)bh * QPAD * 96;
    const size_t kbase = (size_t)bh * KPAD * 96;

    short8v qa[2][3];
    #pragma unroll
    for (int s2 = 0; s2 < 2; ++s2)
        #pragma unroll
        for (int kf = 0; kf < 3; ++kf)
            qa[s2][kf] = *(const short8v*)
                &Q[qbase + (size_t)(q0 + s2 * 16 + c) * 96 + kf * 32 + g * 8];

    f32x4 oacc[2][6];
    #pragma unroll
    for (int s2 = 0; s2 < 2; ++s2)
        #pragma unroll
        for (int t = 0; t < 6; ++t) oacc[s2][t] = (f32x4){0.f, 0.f, 0.f, 0.f};
    float lsum[2][4] = {{0.f,0.f,0.f,0.f},{0.f,0.f,0.f,0.f}};

    short8v kb[2][6];
#define LOADK(IDX, PR) do {                                                     \
    _Pragma("unroll")                                                           \
    for (int h = 0; h < 2; ++h)                                                 \
        _Pragma("unroll")                                                       \
        for (int kf = 0; kf < 3; ++kf)                                          \
            kb[IDX][h * 3 + kf] = *(const short8v*)                             \
                &K[kbase + (size_t)((PR) * 32 + h * 16 + c) * 96 + kf * 32 + g * 8]; \
    } while (0)

    LOADK(0, 0);

    #pragma unroll
    for (int pr = 0; pr < 13; ++pr) {
        const int cur = pr & 1, nxt = cur ^ 1;

        // VT loads for this pr — issued before softmax so they fly under it
        short8v vt[6];
        #pragma unroll
        for (int t = 0; t < 6; ++t)
            vt[t] = *(const short8v*)
                &VT[kbase + (size_t)(t * 16 + c) * KPAD + pr * 32 + g * 8];

        // QK^T for both subtiles, both 16-col halves
        f32x4 sacc[2][2];
        __builtin_amdgcn_s_setprio(1);
        #pragma unroll
        for (int s2 = 0; s2 < 2; ++s2)
            #pragma unroll
            for (int h = 0; h < 2; ++h) {
                f32x4 sa = (f32x4){0.f, 0.f, 0.f, 0.f};
                sa = __builtin_amdgcn_mfma_f32_16x16x32_bf16(qa[s2][0], kb[cur][h*3+0], sa, 0, 0, 0);
                sa = __builtin_amdgcn_mfma_f32_16x16x32_bf16(qa[s2][1], kb[cur][h*3+1], sa, 0, 0, 0);
                sa = __builtin_amdgcn_mfma_f32_16x16x32_bf16(qa[s2][2], kb[cur][h*3+2], sa, 0, 0, 0);
                sacc[s2][h] = sa;
            }
        __builtin_amdgcn_s_setprio(0);

        // prefetch next pr's K
        if (pr < 12) LOADK(nxt, pr + 1);

        // softmax numerator + route into A-frag-linear LDS slots
        #pragma unroll
        for (int s2 = 0; s2 < 2; ++s2)
            #pragma unroll
            for (int h = 0; h < 2; ++h) {
                const int jcol = pr * 32 + h * 16 + c;
                #pragma unroll
                for (int r = 0; r < 4; ++r) {
                    float s = sacc[s2][h][r];
                    if (jcol >= NKV_) s = -1e30f;
                    const float p = __expf(s);
                    lsum[s2][r] += p;
                    const int q    = g * 4 + r;
                    const int j    = h * 16 + c;
                    const int dstL = q | ((j >> 3) << 4);
                    plds[w][s2][dstL * 8 + (j & 7)] = f2bf(p);
                }
            }
        asm volatile("s_waitcnt lgkmcnt(0)" ::: "memory");
        __builtin_amdgcn_sched_barrier(0);
        const short8v pa0 = *(const short8v*)&plds[w][0][lane * 8];
        const short8v pa1 = *(const short8v*)&plds[w][1][lane * 8];

        __builtin_amdgcn_s_setprio(1);
        #pragma unroll
        for (int t = 0; t < 6; ++t)
            oacc[0][t] = __builtin_amdgcn_mfma_f32_16x16x32_bf16(pa0, vt[t], oacc[0][t], 0, 0, 0);
        #pragma unroll
        for (int t = 0; t < 6; ++t)
            oacc[1][t] = __builtin_amdgcn_mfma_f32_16x16x32_bf16(pa1, vt[t], oacc[1][t], 0, 0, 0);
        __builtin_amdgcn_s_setprio(0);
    }
#undef LOADK

    float linv[2][4];
    #pragma unroll
    for (int s2 = 0; s2 < 2; ++s2)
        #pragma unroll
        for (int r = 0; r < 4; ++r) {
            float s = lsum[s2][r];
            s += __shfl_xor(s, 1, 64);
            s += __shfl_xor(s, 2, 64);
            s += __shfl_xor(s, 4, 64);
            s += __shfl_xor(s, 8, 64);
            linv[s2][r] = 1.f / s;
        }

    #pragma unroll
    for (int s2 = 0; s2 < 2; ++s2)
        #pragma unroll
        for (int t = 0; t < 6; ++t)
            #pragma unroll
            for (int r = 0; r < 4; ++r) {
                const int row = q0 + s2 * 16 + g * 4 + r;
                if (row < N_)
                    Out[((size_t)(b * N_ + row)) * 768 + hh * 96 + t * 16 + c] =
                        f2bf(oacc[s2][t][r] * linv[s2][r]);
            }
}

// ---------------------------------------------------------------------------
extern "C" void kernel_launch(void* const* d_in, const int* in_sizes, int n_in,
                              void* d_out, int out_size, void* d_ws, size_t ws_size,
                              hipStream_t stream)
{
    const float* x     = (const float*)d_in[0];
    const float* Wqkv  = (const float*)d_in[1];
    const float* bqkv  = (const float*)d_in[2];
    const float* Wproj = (const float*)d_in[3];
    const float* bproj = (const float*)d_in[4];
    const float* cwq   = (const float*)d_in[5];
    const float* cwk   = (const float*)d_in[6];
    const float* cwv   = (const float*)d_in[7];
    const float* lnqg  = (const float*)d_in[8];
    const float* lnqb  = (const float*)d_in[9];
    const float* lnkg  = (const float*)d_in[10];
    const float* lnkb  = (const float*)d_in[11];
    const float* lnvg  = (const float*)d_in[12];
    const float* lnvb  = (const float*)d_in[13];

    u16* ws = (u16*)d_ws;
    u16* qkv_raw = ws;                       // 3 x [B][NH][N][D] bf16
    u16* q16 = qkv_raw + 3 * QKV1;           // [64][QPAD][96]
    u16* k16 = q16 + (size_t)64 * QPAD * 96; // [64][KPAD][96]
    u16* vt16 = k16 + (size_t)64 * KPAD * 96;// [64][96][KPAD] (transposed)
    u16* x16    = vt16 + (size_t)64 * KPAD * 96;  // [12552][768]
    u16* Wqkvt  = x16 + (size_t)M_ * 768;         // [2304][768]
    u16* Wprojt = Wqkvt + (size_t)2304 * 768;     // [768][768]
    u16* attn16 = qkv_raw;                   // alias: raw dead after pooling
    float* out = (float*)d_out;

    // 0) converts / transposes / VT pad zero
    cvt_f32_to_bf16<<<(M_ * 768 / 4 + 255) / 256, 256, 0, stream>>>(x, x16, M_ * 768 / 4);
    transpose_cvt<<<dim3(2304 / 32, 768 / 32), 256, 0, stream>>>(Wqkv, Wqkvt, 2304);
    transpose_cvt<<<dim3(768 / 32, 768 / 32), 256, 0, stream>>>(Wproj, Wprojt, 768);
    zero_pad_vt<<<(64 * 96 * (KPAD - NKV_) + 255) / 256, 256, 0, stream>>>(vt16);

    // 1) qkv GEMM (pipelined MFMA) with bf16 scatter into q/k/v
    gemm_bf16_kernel<2304, true><<<18 * 99, 256, 0, stream>>>(x16, Wqkvt, bqkv, qkv_raw);

    // 2) block-level pool + LN (one block per (bh, to))
    pool_ln_block_kernel<1, 14, 14, 0><<<512, 256, POOL_LDS_B, stream>>>(
        qkv_raw, cwq, lnqg, lnqb, q16, QPAD, SCALE_);
    pool_ln_block_kernel<2, 7, 7, 1><<<512, 256, POOL_LDS_B, stream>>>(
        qkv_raw + QKV1, cwk, lnkg, lnkb, k16, KPAD, 1.f);
    pool_ln_block_kernel<2, 7, 7, 2><<<512, 256, POOL_LDS_B, stream>>>(
        qkv_raw + 2 * QKV1, cwv, lnvg, lnvb, vt16, KPAD, 1.f);

    // 3) MFMA attention v2 -> bf16 [M_][768]
    attn_mfma_kernel<<<13 * 64, 256, 0, stream>>>(q16, k16, vt16, attn16);

    // 4) output projection (pipelined MFMA) -> fp32 d_out
    gemm_bf16_kernel<768, false><<<6 * 99, 256, 0, stream>>>(attn16, Wprojt, bproj, out);
}

// Round 9
// 265.261 us; speedup vs baseline: 21.8212x; 1.0333x over previous
//
#include <hip/hip_runtime.h>
#include <hip/hip_bf16.h>
#include <math.h>

#define B_   8
#define NH_  8
#define D_   96
#define C_   768
#define N_   1569          // 8*14*14 + 1
#define NKV_ 393           // 8*7*7 + 1
#define M_   (B_*N_)       // 12552
#define QKV1 ((size_t)B_*NH_*N_*D_)    // 9,639,936 elems per tensor
#define QPAD 1664          // padded q rows per slab (13 tiles of 128)
#define KPAD 416           // padded kv rows per slab (13 tiles of 32)
#define SCALE_ 0.10206207261596575f    // 96^-0.5

using short8v = __attribute__((ext_vector_type(8))) short;
using f32x4   = __attribute__((ext_vector_type(4))) float;
typedef unsigned short u16;

#define GLOAD_LDS16(g, l) __builtin_amdgcn_global_load_lds( \
    (const __attribute__((address_space(1))) void*)(g),     \
    (__attribute__((address_space(3))) void*)(l), 16, 0, 0)

static __device__ __forceinline__ u16 f2bf(float f) {
    __hip_bfloat16 b = __float2bfloat16(f);
    return *(u16*)&b;
}
static __device__ __forceinline__ float bf2f(u16 v) {
    return __bfloat162float(*(const __hip_bfloat16*)&v);
}

// bijective XCD swizzle (m204): consecutive swizzled ids land on one XCD
static __device__ __forceinline__ unsigned xcd_swizzle(unsigned orig, unsigned nwg) {
    const unsigned qq = nwg >> 3, rr = nwg & 7;
    const unsigned xcd = orig & 7, loc = orig >> 3;
    return (xcd < rr ? xcd * (qq + 1) : rr * (qq + 1) + (xcd - rr) * qq) + loc;
}

// ---------------------------------------------------------------------------
// fp32 -> bf16 flat convert (n4 float4 chunks)
// ---------------------------------------------------------------------------
__global__ __launch_bounds__(256)
void cvt_f32_to_bf16(const float* __restrict__ in, u16* __restrict__ out, int n4)
{
    const int i = blockIdx.x * 256 + threadIdx.x;
    if (i < n4) {
        const float4 v = ((const float4*)in)[i];
        ushort4 o;
        o.x = f2bf(v.x); o.y = f2bf(v.y); o.z = f2bf(v.z); o.w = f2bf(v.w);
        ((ushort4*)out)[i] = o;
    }
}

// ---------------------------------------------------------------------------
// W [768][ncols] fp32  ->  Wt [ncols][768] bf16   (32x32 LDS tiles)
// ---------------------------------------------------------------------------
__global__ __launch_bounds__(256)
void transpose_cvt(const float* __restrict__ W, u16* __restrict__ Wt, int ncols)
{
    __shared__ float tile[32][33];
    const int tx = threadIdx.x & 31, ty = threadIdx.x >> 5;   // 32 x 8
    const int n0 = blockIdx.x * 32, k0 = blockIdx.y * 32;
    #pragma unroll
    for (int i = 0; i < 4; ++i)
        tile[ty + i * 8][tx] = W[(size_t)(k0 + ty + i * 8) * ncols + n0 + tx];
    __syncthreads();
    #pragma unroll
    for (int i = 0; i < 4; ++i)
        Wt[(size_t)(n0 + ty + i * 8) * 768 + k0 + tx] = f2bf(tile[tx][ty + i * 8]);
}

// ---------------------------------------------------------------------------
// zero V^T pad columns (j in [NKV_, KPAD)) — required finite for PV MFMA
// ---------------------------------------------------------------------------
__global__ __launch_bounds__(256)
void zero_pad_vt(u16* __restrict__ vt)
{
    const int i = blockIdx.x * 256 + threadIdx.x;
    const int total = 64 * 96 * (KPAD - NKV_);
    if (i < total) {
        const int j = i % (KPAD - NKV_);
        const int rest = i / (KPAD - NKV_);     // slab*96 + d
        vt[(size_t)rest * KPAD + NKV_ + j] = 0;
    }
}

// ---------------------------------------------------------------------------
// bf16 MFMA GEMM, counted-vmcnt pipeline (T3+T4) + LDS XOR swizzle (T2).
// 512 threads / 8 waves (2x4), 64x32 per wave -> 4 waves/SIMD at 64KB LDS
// for cross-block latency hiding. T5 setprio around MFMA cluster.
// ---------------------------------------------------------------------------
template<int NC, bool SCATTER>
__global__ __launch_bounds__(512)
void gemm_bf16_kernel(const u16* __restrict__ A, const u16* __restrict__ Bt,
                      const float* __restrict__ bias, void* __restrict__ outp)
{
    constexpr int NXT = NC / 128;
    __shared__ alignas(16) u16 As[2][128 * 64];
    __shared__ alignas(16) u16 Bs[2][128 * 64];

    const int tid  = threadIdx.x;
    const int w    = tid >> 6, lane = tid & 63;
    const int c    = lane & 15, g = lane >> 4;
    const int wm   = w >> 2, wn = w & 3;      // 2 x 4 wave grid
    const int lrow = lane >> 3, lcol = lane & 7;

    const unsigned wg = xcd_swizzle(blockIdx.x, gridDim.x);
    const int m0 = (int)(wg / NXT) * 128;
    const int n0 = (int)(wg % NXT) * 128;

    f32x4 acc[4][2];
    #pragma unroll
    for (int i = 0; i < 4; ++i)
        #pragma unroll
        for (int j = 0; j < 2; ++j) acc[i][j] = (f32x4){0.f, 0.f, 0.f, 0.f};

    // 4 loads/thread per STAGE (2 A + 2 B); 8 waves cover 64 rows per step
#define STAGE(BUF, K0) do {                                                      \
    _Pragma("unroll")                                                            \
    for (int t = 0; t < 2; ++t) {                                                \
        const int r = t * 64 + w * 8;                                            \
        const int row = r + lrow;                                                \
        const int scol = (lcol ^ (row & 7)) * 8;                                 \
        int m = m0 + row; if (m >= M_) m = M_ - 1;                               \
        GLOAD_LDS16(&A[(size_t)m * 768 + (K0) + scol], &As[BUF][r * 64]);        \
        GLOAD_LDS16(&Bt[(size_t)(n0 + row) * 768 + (K0) + scol],                 \
                    &Bs[BUF][r * 64]);                                           \
    } } while (0)

    const int xora = (g ^ (c & 7)) * 8;          // kk=0: logical col16 = g
    const int xorb = ((4 + g) ^ (c & 7)) * 8;    // kk=1: logical col16 = 4+g

#define KSTEP(BUF, LAST, PREF, KNEXT) do {                                       \
    if (LAST) asm volatile("s_waitcnt vmcnt(0)" ::: "memory");                   \
    else      asm volatile("s_waitcnt vmcnt(4)" ::: "memory");                   \
    __builtin_amdgcn_s_barrier();                                                \
    short8v a0[4], a1[4], b0[2], b1[2];                                          \
    _Pragma("unroll")                                                            \
    for (int i = 0; i < 4; ++i) {                                                \
        const int ra = (wm * 64 + i * 16 + c) * 64;                              \
        a0[i] = *(const short8v*)&As[BUF][ra + xora];                            \
        a1[i] = *(const short8v*)&As[BUF][ra + xorb];                            \
    }                                                                            \
    _Pragma("unroll")                                                            \
    for (int j = 0; j < 2; ++j) {                                                \
        const int rb = (wn * 32 + j * 16 + c) * 64;                              \
        b0[j] = *(const short8v*)&Bs[BUF][rb + xora];                            \
        b1[j] = *(const short8v*)&Bs[BUF][rb + xorb];                            \
    }                                                                            \
    asm volatile("s_waitcnt lgkmcnt(0)" ::: "memory");                           \
    __builtin_amdgcn_sched_barrier(0);                                           \
    __builtin_amdgcn_s_barrier();                                                \
    if (PREF) STAGE(BUF, KNEXT);                                                 \
    __builtin_amdgcn_s_setprio(1);                                               \
    _Pragma("unroll")                                                            \
    for (int i = 0; i < 4; ++i)                                                  \
        _Pragma("unroll")                                                        \
        for (int j = 0; j < 2; ++j)                                              \
            acc[i][j] = __builtin_amdgcn_mfma_f32_16x16x32_bf16(                 \
                a0[i], b0[j], acc[i][j], 0, 0, 0);                               \
    _Pragma("unroll")                                                            \
    for (int i = 0; i < 4; ++i)                                                  \
        _Pragma("unroll")                                                        \
        for (int j = 0; j < 2; ++j)                                              \
            acc[i][j] = __builtin_amdgcn_mfma_f32_16x16x32_bf16(                 \
                a1[i], b1[j], acc[i][j], 0, 0, 0);                               \
    __builtin_amdgcn_s_setprio(0);                                               \
    } while (0)

    STAGE(0, 0);
    STAGE(1, 64);
    #pragma unroll
    for (int tt = 0; tt < 5; ++tt) {
        KSTEP(0, false, true, (2 * tt + 2) * 64);
        KSTEP(1, false, true, (2 * tt + 3) * 64);
    }
    KSTEP(0, false, false, 0);
    KSTEP(1, true,  false, 0);
#undef STAGE
#undef KSTEP

    #pragma unroll
    for (int i = 0; i < 4; ++i) {
        const int mrow = m0 + wm * 64 + i * 16 + g * 4;
        #pragma unroll
        for (int j = 0; j < 2; ++j) {
            const int ncol = n0 + wn * 32 + j * 16 + c;
            const float bv = bias[ncol];
            if constexpr (SCATTER) {
                u16* out = (u16*)outp;
                const int s   = ncol / C_;          // 0=q,1=k,2=v
                const int rem = ncol - s * C_;
                const int hh  = rem / D_;
                const int dd  = rem - hh * D_;
                #pragma unroll
                for (int r = 0; r < 4; ++r) {
                    const int m = mrow + r;
                    if (m < M_) {
                        const int bb2 = m / N_;
                        const int n = m - bb2 * N_;
                        out[(size_t)s * QKV1 +
                            ((size_t)(bb2 * NH_ + hh) * N_ + n) * D_ + dd] = f2bf(acc[i][j][r] + bv);
                    }
                }
            } else {
                float* out = (float*)outp;
                #pragma unroll
                for (int r = 0; r < 4; ++r) {
                    const int m = mrow + r;
                    if (m < M_) out[(size_t)m * NC + ncol] = acc[i][j][r] + bv;
                }
            }
        }
    }
}

// ---------------------------------------------------------------------------
// Block-level pool+LN: one block per (bh, to). Stage 3 input t-planes into
// LDS via global_load_lds, compute all outputs. MODE: 0=q, 1=k, 2=v^T.
// ---------------------------------------------------------------------------
#define PLANE_B 37632              // 196*192 bytes per t-plane
#define POOL_LDS_B (114688 + 96*27*4)
template<int STRIDE, int OH, int OW, int MODE>
__global__ __launch_bounds__(256, 1)
void pool_ln_block_kernel(const u16* __restrict__ in, const float* __restrict__ cw,
                          const float* __restrict__ g, const float* __restrict__ bta,
                          u16* __restrict__ out, int tokstride, float oscale)
{
    extern __shared__ u16 smem[];              // [3][196][96] (+pad to 114688B)
    float* wsm2 = (float*)(smem + 57344);      // [27][96] transposed weights

    const int tid = threadIdx.x;
    const int wv = tid >> 6, lane = tid & 63;

    for (int i = tid; i < 96 * 27; i += 256) {
        const int tap = i / 96, ch = i - tap * 96;
        wsm2[i] = cw[ch * 27 + tap];
    }

    const unsigned wg = xcd_swizzle(blockIdx.x, gridDim.x);
    const int bh = (int)(wg >> 3);
    const int to = (int)(wg & 7);
    const size_t inbase = (size_t)bh * N_ * 96;

    #pragma unroll
    for (int it = 0; it < 28; ++it) {
        const int byte = (it * 256 + tid) * 16;
        int plane = byte / PLANE_B; if (plane > 2) plane = 2;
        const int rem = byte - plane * PLANE_B;
        const int tok = rem / 192;
        const int chb = rem - tok * 192;
        int t = to - 1 + plane; if (t < 0) t = 0; if (t > 7) t = 7;
        const u16* gsrc = in + inbase + (size_t)(1 + t * 196 + tok) * 96 + (chb >> 1);
        GLOAD_LDS16(gsrc, smem + (size_t)(it * 256 + wv * 64) * 8);
    }
    __syncthreads();

    const int l = lane < 48 ? lane : 47;
    const bool act = lane < 48;

    float wg0[27], wg1[27];
    #pragma unroll
    for (int tap = 0; tap < 27; ++tap) {
        const float2 wp = *(const float2*)&wsm2[tap * 96 + 2 * l];
        wg0[tap] = wp.x; wg1[tap] = wp.y;
    }
    const float gam0 = g[2 * l],     bet0 = bta[2 * l];
    const float gam1 = g[2 * l + 1], bet1 = bta[2 * l + 1];

    for (int ho = wv; ho < OH; ho += 4) {
        float a0[OW], a1[OW];
        #pragma unroll
        for (int wo = 0; wo < OW; ++wo) { a0[wo] = 0.f; a1[wo] = 0.f; }

        #pragma unroll
        for (int dt = 0; dt < 3; ++dt) {
            const int t = to - 1 + dt;
            if (t < 0 || t > 7) continue;
            #pragma unroll
            for (int dh = 0; dh < 3; ++dh) {
                const int h = ho * STRIDE - 1 + dh;
                if (h < 0 || h >= 14) continue;
                float xl[14], xh[14];
                #pragma unroll
                for (int iw = 0; iw < 14; ++iw) {
                    const unsigned u = *(const unsigned*)
                        &smem[(dt * 196 + h * 14 + iw) * 96 + 2 * l];
                    xl[iw] = __uint_as_float(u << 16);
                    xh[iw] = __uint_as_float(u & 0xffff0000u);
                }
                const int tapb = dt * 9 + dh * 3;
                #pragma unroll
                for (int wo = 0; wo < OW; ++wo)
                    #pragma unroll
                    for (int dw = 0; dw < 3; ++dw) {
                        const int iw = wo * STRIDE - 1 + dw;
                        if (iw < 0 || iw >= 14) continue;   // compile-time
                        a0[wo] += wg0[tapb + dw] * xl[iw];
                        a1[wo] += wg1[tapb + dw] * xh[iw];
                    }
            }
        }

        #pragma unroll
        for (int wo = 0; wo < OW; ++wo) {
            const float va = act ? a0[wo] : 0.f, vb = act ? a1[wo] : 0.f;
            float s = va + vb;
            #pragma unroll
            for (int off = 32; off; off >>= 1) s += __shfl_xor(s, off, 64);
            float sq = va * va + vb * vb;
            #pragma unroll
            for (int off = 32; off; off >>= 1) sq += __shfl_xor(sq, off, 64);
            const float mu = s * (1.f / 96.f);
            const float rstd = rsqrtf(sq * (1.f / 96.f) - mu * mu + 1e-5f);
            const float y0 = ((va - mu) * rstd * gam0 + bet0) * oscale;
            const float y1 = ((vb - mu) * rstd * gam1 + bet1) * oscale;
            const int tok = 1 + (to * OH + ho) * OW + wo;
            if (act) {
                if constexpr (MODE == 2) {
                    out[((size_t)bh * 96 + 2 * l) * KPAD + tok] = f2bf(y0);
                    out[((size_t)bh * 96 + 2 * l + 1) * KPAD + tok] = f2bf(y1);
                } else {
                    const unsigned pk = (unsigned)f2bf(y0) | ((unsigned)f2bf(y1) << 16);
                    *(unsigned*)&out[((size_t)bh * tokstride + tok) * 96 + 2 * l] = pk;
                }
            }
        }
    }

    if (to == 0 && wv == 3) {        // cls token: LN only
        const unsigned u = *(const unsigned*)&in[inbase + 2 * l];
        const float va = act ? __uint_as_float(u << 16) : 0.f;
        const float vb = act ? __uint_as_float(u & 0xffff0000u) : 0.f;
        float s = va + vb;
        #pragma unroll
        for (int off = 32; off; off >>= 1) s += __shfl_xor(s, off, 64);
        float sq = va * va + vb * vb;
        #pragma unroll
        for (int off = 32; off; off >>= 1) sq += __shfl_xor(sq, off, 64);
        const float mu = s * (1.f / 96.f);
        const float rstd = rsqrtf(sq * (1.f / 96.f) - mu * mu + 1e-5f);
        const float y0 = ((va - mu) * rstd * gam0 + bet0) * oscale;
        const float y1 = ((vb - mu) * rstd * gam1 + bet1) * oscale;
        if (act) {
            if constexpr (MODE == 2) {
                out[((size_t)bh * 96 + 2 * l) * KPAD] = f2bf(y0);
                out[((size_t)bh * 96 + 2 * l + 1) * KPAD] = f2bf(y1);
            } else {
                const unsigned pk = (unsigned)f2bf(y0) | ((unsigned)f2bf(y1) << 16);
                *(unsigned*)&out[(size_t)bh * tokstride * 96 + 2 * l] = pk;
            }
        }
    }
}

// ---------------------------------------------------------------------------
// MFMA attention v2 -> bf16 [M_][768]. 32 q-rows/wave (2 subtiles), K reg
// double-buffer prefetch, VT loads hoisted before softmax. Q pre-scaled.
// ---------------------------------------------------------------------------
__global__ __launch_bounds__(256)
void attn_mfma_kernel(const u16* __restrict__ Q, const u16* __restrict__ K,
                      const u16* __restrict__ VT, u16* __restrict__ Out)
{
    __shared__ alignas(16) u16 plds[4][2][512];   // per-wave, per-subtile P tile
    const int tid  = threadIdx.x;
    const int w    = tid >> 6, lane = tid & 63;
    const int c    = lane & 15, g = lane >> 4;

    const unsigned wg = xcd_swizzle(blockIdx.x, gridDim.x);
    const int bh = (int)(wg / 13);
    const int b  = bh >> 3, hh = bh & 7;
    const int q0 = (int)(wg % 13) * 128 + w * 32;

    const size_t qbase = (size_t)bh * QPAD * 96;
    const size_t kbase = (size_t)bh * KPAD * 96;

    short8v qa[2][3];
    #pragma unroll
    for (int s2 = 0; s2 < 2; ++s2)
        #pragma unroll
        for (int kf = 0; kf < 3; ++kf)
            qa[s2][kf] = *(const short8v*)
                &Q[qbase + (size_t)(q0 + s2 * 16 + c) * 96 + kf * 32 + g * 8];

    f32x4 oacc[2][6];
    #pragma unroll
    for (int s2 = 0; s2 < 2; ++s2)
        #pragma unroll
        for (int t = 0; t < 6; ++t) oacc[s2][t] = (f32x4){0.f, 0.f, 0.f, 0.f};
    float lsum[2][4] = {{0.f,0.f,0.f,0.f},{0.f,0.f,0.f,0.f}};

    short8v kb[2][6];
#define LOADK(IDX, PR) do {                                                     \
    _Pragma("unroll")                                                           \
    for (int h = 0; h < 2; ++h)                                                 \
        _Pragma("unroll")                                                       \
        for (int kf = 0; kf < 3; ++kf)                                          \
            kb[IDX][h * 3 + kf] = *(const short8v*)                             \
                &K[kbase + (size_t)((PR) * 32 + h * 16 + c) * 96 + kf * 32 + g * 8]; \
    } while (0)

    LOADK(0, 0);

    #pragma unroll
    for (int pr = 0; pr < 13; ++pr) {
        const int cur = pr & 1, nxt = cur ^ 1;

        short8v vt[6];
        #pragma unroll
        for (int t = 0; t < 6; ++t)
            vt[t] = *(const short8v*)
                &VT[kbase + (size_t)(t * 16 + c) * KPAD + pr * 32 + g * 8];

        f32x4 sacc[2][2];
        __builtin_amdgcn_s_setprio(1);
        #pragma unroll
        for (int s2 = 0; s2 < 2; ++s2)
            #pragma unroll
            for (int h = 0; h < 2; ++h) {
                f32x4 sa = (f32x4){0.f, 0.f, 0.f, 0.f};
                sa = __builtin_amdgcn_mfma_f32_16x16x32_bf16(qa[s2][0], kb[cur][h*3+0], sa, 0, 0, 0);
                sa = __builtin_amdgcn_mfma_f32_16x16x32_bf16(qa[s2][1], kb[cur][h*3+1], sa, 0, 0, 0);
                sa = __builtin_amdgcn_mfma_f32_16x16x32_bf16(qa[s2][2], kb[cur][h*3+2], sa, 0, 0, 0);
                sacc[s2][h] = sa;
            }
        __builtin_amdgcn_s_setprio(0);

        if (pr < 12) LOADK(nxt, pr + 1);

        #pragma unroll
        for (int s2 = 0; s2 < 2; ++s2)
            #pragma unroll
            for (int h = 0; h < 2; ++h) {
                const int jcol = pr * 32 + h * 16 + c;
                #pragma unroll
                for (int r = 0; r < 4; ++r) {
                    float s = sacc[s2][h][r];
                    if (jcol >= NKV_) s = -1e30f;
                    const float p = __expf(s);
                    lsum[s2][r] += p;
                    const int q    = g * 4 + r;
                    const int j    = h * 16 + c;
                    const int dstL = q | ((j >> 3) << 4);
                    plds[w][s2][dstL * 8 + (j & 7)] = f2bf(p);
                }
            }
        asm volatile("s_waitcnt lgkmcnt(0)" ::: "memory");
        __builtin_amdgcn_sched_barrier(0);
        const short8v pa0 = *(const short8v*)&plds[w][0][lane * 8];
        const short8v pa1 = *(const short8v*)&plds[w][1][lane * 8];

        __builtin_amdgcn_s_setprio(1);
        #pragma unroll
        for (int t = 0; t < 6; ++t)
            oacc[0][t] = __builtin_amdgcn_mfma_f32_16x16x32_bf16(pa0, vt[t], oacc[0][t], 0, 0, 0);
        #pragma unroll
        for (int t = 0; t < 6; ++t)
            oacc[1][t] = __builtin_amdgcn_mfma_f32_16x16x32_bf16(pa1, vt[t], oacc[1][t], 0, 0, 0);
        __builtin_amdgcn_s_setprio(0);
    }
#undef LOADK

    float linv[2][4];
    #pragma unroll
    for (int s2 = 0; s2 < 2; ++s2)
        #pragma unroll
        for (int r = 0; r < 4; ++r) {
            float s = lsum[s2][r];
            s += __shfl_xor(s, 1, 64);
            s += __shfl_xor(s, 2, 64);
            s += __shfl_xor(s, 4, 64);
            s += __shfl_xor(s, 8, 64);
            linv[s2][r] = 1.f / s;
        }

    #pragma unroll
    for (int s2 = 0; s2 < 2; ++s2)
        #pragma unroll
        for (int t = 0; t < 6; ++t)
            #pragma unroll
            for (int r = 0; r < 4; ++r) {
                const int row = q0 + s2 * 16 + g * 4 + r;
                if (row < N_)
                    Out[((size_t)(b * N_ + row)) * 768 + hh * 96 + t * 16 + c] =
                        f2bf(oacc[s2][t][r] * linv[s2][r]);
            }
}

// ---------------------------------------------------------------------------
extern "C" void kernel_launch(void* const* d_in, const int* in_sizes, int n_in,
                              void* d_out, int out_size, void* d_ws, size_t ws_size,
                              hipStream_t stream)
{
    const float* x     = (const float*)d_in[0];
    const float* Wqkv  = (const float*)d_in[1];
    const float* bqkv  = (const float*)d_in[2];
    const float* Wproj = (const float*)d_in[3];
    const float* bproj = (const float*)d_in[4];
    const float* cwq   = (const float*)d_in[5];
    const float* cwk   = (const float*)d_in[6];
    const float* cwv   = (const float*)d_in[7];
    const float* lnqg  = (const float*)d_in[8];
    const float* lnqb  = (const float*)d_in[9];
    const float* lnkg  = (const float*)d_in[10];
    const float* lnkb  = (const float*)d_in[11];
    const float* lnvg  = (const float*)d_in[12];
    const float* lnvb  = (const float*)d_in[13];

    u16* ws = (u16*)d_ws;
    u16* qkv_raw = ws;                       // 3 x [B][NH][N][D] bf16
    u16* q16 = qkv_raw + 3 * QKV1;           // [64][QPAD][96]
    u16* k16 = q16 + (size_t)64 * QPAD * 96; // [64][KPAD][96]
    u16* vt16 = k16 + (size_t)64 * KPAD * 96;// [64][96][KPAD] (transposed)
    u16* x16    = vt16 + (size_t)64 * KPAD * 96;  // [12552][768]
    u16* Wqkvt  = x16 + (size_t)M_ * 768;         // [2304][768]
    u16* Wprojt = Wqkvt + (size_t)2304 * 768;     // [768][768]
    u16* attn16 = qkv_raw;                   // alias: raw dead after pooling
    float* out = (float*)d_out;

    // 0) converts / transposes / VT pad zero
    cvt_f32_to_bf16<<<(M_ * 768 / 4 + 255) / 256, 256, 0, stream>>>(x, x16, M_ * 768 / 4);
    transpose_cvt<<<dim3(2304 / 32, 768 / 32), 256, 0, stream>>>(Wqkv, Wqkvt, 2304);
    transpose_cvt<<<dim3(768 / 32, 768 / 32), 256, 0, stream>>>(Wproj, Wprojt, 768);
    zero_pad_vt<<<(64 * 96 * (KPAD - NKV_) + 255) / 256, 256, 0, stream>>>(vt16);

    // 1) qkv GEMM (8-wave pipelined MFMA) with bf16 scatter into q/k/v
    gemm_bf16_kernel<2304, true><<<18 * 99, 512, 0, stream>>>(x16, Wqkvt, bqkv, qkv_raw);

    // 2) block-level pool + LN (one block per (bh, to))
    pool_ln_block_kernel<1, 14, 14, 0><<<512, 256, POOL_LDS_B, stream>>>(
        qkv_raw, cwq, lnqg, lnqb, q16, QPAD, SCALE_);
    pool_ln_block_kernel<2, 7, 7, 1><<<512, 256, POOL_LDS_B, stream>>>(
        qkv_raw + QKV1, cwk, lnkg, lnkb, k16, KPAD, 1.f);
    pool_ln_block_kernel<2, 7, 7, 2><<<512, 256, POOL_LDS_B, stream>>>(
        qkv_raw + 2 * QKV1, cwv, lnvg, lnvb, vt16, KPAD, 1.f);

    // 3) MFMA attention v2 -> bf16 [M_][768]
    attn_mfma_kernel<<<13 * 64, 256, 0, stream>>>(q16, k16, vt16, attn16);

    // 4) output projection (8-wave pipelined MFMA) -> fp32 d_out
    gemm_bf16_kernel<768, false><<<6 * 99, 512, 0, stream>>>(attn16, Wprojt, bproj, out);
}